// Round 2
// baseline (2059.533 us; speedup 1.0000x reference)
//
#include <hip/hip_runtime.h>
#include <hip/hip_bf16.h>
#include <cstdint>
#include <cstddef>

#define TDIM 2048
#define NH 8

using f32x4 = __attribute__((ext_vector_type(4))) float;
using s16x8 = __attribute__((ext_vector_type(8))) short;

__device__ __forceinline__ float sigm(float x) { return 1.0f / (1.0f + __expf(-x)); }
__device__ __forceinline__ float2 fma2(float2 a, float2 b, float2 c) {
    return make_float2(fmaf(a.x, b.x, c.x), fmaf(a.y, b.y, c.y));
}
__device__ __forceinline__ float2 mul2(float2 a, float2 b) {
    return make_float2(a.x * b.x, a.y * b.y);
}

#define GLDS(gp, lp)                                                          \
    __builtin_amdgcn_global_load_lds(                                         \
        (const __attribute__((address_space(1))) void*)(gp),                  \
        (__attribute__((address_space(3))) void*)(lp), 16, 0, 0)

// ---------------------------------------------------------------- pack kernels
__global__ __launch_bounds__(256) void pack_f32_bf16_kernel(
    const float* __restrict__ src, __hip_bfloat16* __restrict__ dst, int n4)
{
    int i = blockIdx.x * 256 + threadIdx.x;
    if (i >= n4) return;
    float4 v = *(const float4*)(src + (size_t)i * 4);
    size_t o = (size_t)i * 4;
    dst[o + 0] = __float2bfloat16(v.x);
    dst[o + 1] = __float2bfloat16(v.y);
    dst[o + 2] = __float2bfloat16(v.z);
    dst[o + 3] = __float2bfloat16(v.w);
}

__global__ __launch_bounds__(256) void pack_w_kernel(
    const float* __restrict__ Wq, const float* __restrict__ Wk,
    const float* __restrict__ Wv, const float* __restrict__ Wa,
    const float* __restrict__ Wb, const float* __restrict__ Wg,
    __hip_bfloat16* __restrict__ dst)
{
    int e = blockIdx.x * 256 + threadIdx.x;  // < 4224*1024
    int r = e >> 10, c = e & 1023;
    float vv;
    if      (r <  512) vv = Wq[(size_t)r * 1024 + c];
    else if (r < 1024) vv = Wk[(size_t)(r -  512) * 1024 + c];
    else if (r < 2048) vv = Wv[(size_t)(r - 1024) * 1024 + c];
    else if (r < 3072) vv = Wa[(size_t)(r - 2048) * 1024 + c];
    else if (r < 3080) vv = Wb[(size_t)(r - 3072) * 1024 + c];
    else if (r < 4104) vv = Wg[(size_t)(r - 3080) * 1024 + c];
    else               vv = 0.0f;
    dst[e] = __float2bfloat16(vv);
}

// ---------------------------------------------------------------- GEMM 1 (fused epilogue)
__global__ __launch_bounds__(256) void gemm1_kernel(
    const __hip_bfloat16* __restrict__ A, const __hip_bfloat16* __restrict__ Bw,
    float* __restrict__ qraw, float* __restrict__ kraw, float* __restrict__ vraw,
    float* __restrict__ abuf, float* __restrict__ betab, float* __restrict__ gbuf,
    const float* __restrict__ ba, const float* __restrict__ bb)
{
    constexpr int Kd = 1024;
    __shared__ __attribute__((aligned(16))) __hip_bfloat16 At[128 * 32];
    __shared__ __attribute__((aligned(16))) __hip_bfloat16 Bt[128 * 32];
    const int tid = threadIdx.x;
    const int mBase = blockIdx.x * 128;
    const int nBase = blockIdx.y * 128;
    const int wave = tid >> 6, lane = tid & 63;
    const int wm = (wave >> 1) * 64, wn = (wave & 1) * 64;
    const int quad = lane >> 4, l16 = lane & 15;

    f32x4 acc[4][4];
    for (int i = 0; i < 4; i++)
        for (int j = 0; j < 4; j++)
            for (int r = 0; r < 4; r++) acc[i][j][r] = 0.0f;

    const int srow = tid >> 2;
    const int skk = (tid & 3) * 8;
    const __hip_bfloat16* Ag = A + (size_t)(mBase + srow) * Kd + skk;
    const __hip_bfloat16* Bg = Bw + (size_t)(nBase + srow) * Kd + skk;
    __hip_bfloat16* Al = &At[srow * 32 + skk];
    __hip_bfloat16* Bl = &Bt[srow * 32 + skk];

    for (int k0 = 0; k0 < Kd; k0 += 32) {
        GLDS(Ag + k0, Al);
        GLDS(Ag + k0 + (size_t)64 * Kd, Al + 64 * 32);
        GLDS(Bg + k0, Bl);
        GLDS(Bg + k0 + (size_t)64 * Kd, Bl + 64 * 32);
        __syncthreads();
        s16x8 af[4], bfr[4];
#pragma unroll
        for (int i = 0; i < 4; i++)
            af[i] = *(const s16x8*)&At[(wm + i * 16 + l16) * 32 + quad * 8];
#pragma unroll
        for (int j = 0; j < 4; j++)
            bfr[j] = *(const s16x8*)&Bt[(wn + j * 16 + l16) * 32 + quad * 8];
#pragma unroll
        for (int i = 0; i < 4; i++)
#pragma unroll
            for (int j = 0; j < 4; j++)
                acc[i][j] = __builtin_amdgcn_mfma_f32_16x16x32_bf16(af[i], bfr[j], acc[i][j], 0, 0, 0);
        __syncthreads();
    }

    for (int j = 0; j < 4; j++) {
        int n = nBase + wn + j * 16 + l16;
        for (int i = 0; i < 4; i++) {
            for (int r = 0; r < 4; r++) {
                int m = mBase + wm + i * 16 + quad * 4 + r;
                float val = acc[i][j][r];
                if (n < 512) qraw[(size_t)m * 512 + n] = val;
                else if (n < 1024) kraw[(size_t)m * 512 + n - 512] = val;
                else if (n < 2048) vraw[(size_t)m * 1024 + n - 1024] = val;
                else if (n < 3072) abuf[(size_t)m * 1024 + n - 2048] = sigm(val + ba[n - 2048]);
                else if (n < 3080) betab[(size_t)m * 8 + n - 3072] = sigm(val + bb[n - 3072]);
                else if (n < 4104) gbuf[(size_t)m * 1024 + n - 3080] = sigm(val);
            }
        }
    }
}

// ---------------------------------------------------------------- GEMM 2 (plain)
__global__ __launch_bounds__(256) void gemm2_kernel(
    const __hip_bfloat16* __restrict__ A, const __hip_bfloat16* __restrict__ Bw,
    float* __restrict__ out)
{
    constexpr int Kd = 1024;
    __shared__ __attribute__((aligned(16))) __hip_bfloat16 At[128 * 32];
    __shared__ __attribute__((aligned(16))) __hip_bfloat16 Bt[128 * 32];
    const int tid = threadIdx.x;
    const int mBase = blockIdx.x * 128;
    const int nBase = blockIdx.y * 128;
    const int wave = tid >> 6, lane = tid & 63;
    const int wm = (wave >> 1) * 64, wn = (wave & 1) * 64;
    const int quad = lane >> 4, l16 = lane & 15;

    f32x4 acc[4][4];
    for (int i = 0; i < 4; i++)
        for (int j = 0; j < 4; j++)
            for (int r = 0; r < 4; r++) acc[i][j][r] = 0.0f;

    const int srow = tid >> 2;
    const int skk = (tid & 3) * 8;
    const __hip_bfloat16* Ag = A + (size_t)(mBase + srow) * Kd + skk;
    const __hip_bfloat16* Bg = Bw + (size_t)(nBase + srow) * Kd + skk;
    __hip_bfloat16* Al = &At[srow * 32 + skk];
    __hip_bfloat16* Bl = &Bt[srow * 32 + skk];

    for (int k0 = 0; k0 < Kd; k0 += 32) {
        GLDS(Ag + k0, Al);
        GLDS(Ag + k0 + (size_t)64 * Kd, Al + 64 * 32);
        GLDS(Bg + k0, Bl);
        GLDS(Bg + k0 + (size_t)64 * Kd, Bl + 64 * 32);
        __syncthreads();
        s16x8 af[4], bfr[4];
#pragma unroll
        for (int i = 0; i < 4; i++)
            af[i] = *(const s16x8*)&At[(wm + i * 16 + l16) * 32 + quad * 8];
#pragma unroll
        for (int j = 0; j < 4; j++)
            bfr[j] = *(const s16x8*)&Bt[(wn + j * 16 + l16) * 32 + quad * 8];
#pragma unroll
        for (int i = 0; i < 4; i++)
#pragma unroll
            for (int j = 0; j < 4; j++)
                acc[i][j] = __builtin_amdgcn_mfma_f32_16x16x32_bf16(af[i], bfr[j], acc[i][j], 0, 0, 0);
        __syncthreads();
    }

    for (int j = 0; j < 4; j++) {
        int n = nBase + wn + j * 16 + l16;
        for (int i = 0; i < 4; i++) {
            for (int r = 0; r < 4; r++) {
                int m = mBase + wm + i * 16 + quad * 4 + r;
                out[(size_t)m * 1024 + n] = acc[i][j][r];
            }
        }
    }
}

// ---------------------------------------------------------------- depthwise causal conv (K=4) + SiLU
__global__ __launch_bounds__(256) void conv_silu_kernel(
    const float* __restrict__ src, const float* __restrict__ w4,
    const float* __restrict__ bias, float* __restrict__ dst,
    int C, int total, float scale)
{
    int e = blockIdx.x * 256 + threadIdx.x;
    if (e >= total) return;
    int c = e % C;
    int bt = e / C;
    int t = bt % TDIM;
    const float* wc = w4 + (size_t)c * 4;
    const float* s = src + (size_t)bt * C + c;
    float acc = bias[c];
    acc = fmaf(s[0], wc[3], acc);
    if (t >= 1) acc = fmaf(s[-C], wc[2], acc);
    if (t >= 2) acc = fmaf(s[-2 * C], wc[1], acc);
    if (t >= 3) acc = fmaf(s[-3 * C], wc[0], acc);
    dst[e] = acc * sigm(acc) * scale;
}

// ---------------------------------------------------------------- gated delta-rule scan v2
// 128 blocks x 64 threads. block -> (b, h, vg of 32 columns).
// lane: ks = lane&1 (half of DK), ci = lane>>1 (column). Each lane holds
// S[ks*32 .. ks*32+31][v] as 16 float2. Reductions = ONE __shfl_xor(,1)
// (DPP quad swap, ~cheap) instead of 3 LDS-pipe shuffles.
#define SCAN_LOAD(KK, QQ, VV, AA, BB, TT) do {                                \
    const float4* kp = (const float4*)(kc + kqBase + (size_t)(TT) * 512);     \
    const float4* qp = (const float4*)(qc + kqBase + (size_t)(TT) * 512);     \
    _Pragma("unroll") for (int j = 0; j < 8; j++) { KK[j] = kp[j]; QQ[j] = qp[j]; } \
    size_t vo = vaBase + (size_t)(TT) * 1024;                                 \
    VV = vc[vo]; AA = ab[vo]; BB = betab[beBase + (size_t)(TT) * 8];          \
} while (0)

#define SCAN_STEP(KK, QQ, VV, AA, BB, TT) do {                                \
    const float2* k2 = (const float2*)KK;                                     \
    const float2* q2 = (const float2*)QQ;                                     \
    float2 d0 = mul2(k2[0], S[0]), d1 = mul2(k2[1], S[1]);                    \
    float2 d2 = mul2(k2[2], S[2]), d3 = mul2(k2[3], S[3]);                    \
    _Pragma("unroll") for (int j = 4; j < 16; j += 4) {                       \
        d0 = fma2(k2[j], S[j], d0);   d1 = fma2(k2[j+1], S[j+1], d1);         \
        d2 = fma2(k2[j+2], S[j+2], d2); d3 = fma2(k2[j+3], S[j+3], d3);       \
    }                                                                         \
    float2 ds = make_float2(d0.x + d1.x + d2.x + d3.x,                        \
                            d0.y + d1.y + d2.y + d3.y);                       \
    float rr = ds.x + ds.y;                                                   \
    rr += __shfl_xor(rr, 1);                                                  \
    float cc = BB * (rr - VV);                                                \
    float2 mcc = make_float2(-cc, -cc);                                       \
    float2 aa2 = make_float2(AA, AA);                                         \
    float2 o0 = make_float2(0.f, 0.f), o1 = o0, o2 = o0, o3 = o0;             \
    _Pragma("unroll") for (int j = 0; j < 16; j += 4) {                       \
        S[j]   = fma2(k2[j],   mcc, mul2(aa2, S[j]));                         \
        S[j+1] = fma2(k2[j+1], mcc, mul2(aa2, S[j+1]));                       \
        S[j+2] = fma2(k2[j+2], mcc, mul2(aa2, S[j+2]));                       \
        S[j+3] = fma2(k2[j+3], mcc, mul2(aa2, S[j+3]));                       \
        o0 = fma2(q2[j], S[j], o0);     o1 = fma2(q2[j+1], S[j+1], o1);       \
        o2 = fma2(q2[j+2], S[j+2], o2); o3 = fma2(q2[j+3], S[j+3], o3);       \
    }                                                                         \
    float2 os = make_float2(o0.x + o1.x + o2.x + o3.x,                        \
                            o0.y + o1.y + o2.y + o3.y);                       \
    float oo = os.x + os.y;                                                   \
    oo += __shfl_xor(oo, 1);                                                  \
    if (ks == 0) ob[vaBase + (size_t)(TT) * 1024] = oo;                       \
} while (0)

__global__ __launch_bounds__(64) void scan_kernel(
    const float* __restrict__ qc, const float* __restrict__ kc,
    const float* __restrict__ vc, const float* __restrict__ ab,
    const float* __restrict__ betab, float* __restrict__ ob)
{
    const int bid = blockIdx.x;
    const int vg = bid & 3, h = (bid >> 2) & 7, b = bid >> 5;
    const int lane = threadIdx.x;
    const int ks = lane & 1, ci = lane >> 1;
    const int v = vg * 32 + ci;
    float2 S[16];
#pragma unroll
    for (int j = 0; j < 16; j++) S[j] = make_float2(0.f, 0.f);
    const size_t kqBase = ((size_t)b * TDIM * NH + h) * 64 + (size_t)ks * 32;  // +t*512
    const size_t vaBase = ((size_t)b * TDIM * NH + h) * 128 + v;               // +t*1024
    const size_t beBase = (size_t)b * TDIM * 8 + h;                            // +t*8

    float4 kA[8], qA[8], kB[8], qB[8];
    float vA, aA, btA, vB, aB, btB;
    SCAN_LOAD(kA, qA, vA, aA, btA, 0);
    for (int t = 0; t < TDIM; t += 2) {
        SCAN_LOAD(kB, qB, vB, aB, btB, t + 1);
        SCAN_STEP(kA, qA, vA, aA, btA, t);
        int t2 = (t + 2 < TDIM) ? (t + 2) : 0;
        SCAN_LOAD(kA, qA, vA, aA, btA, t2);
        SCAN_STEP(kB, qB, vB, aB, btB, t + 1);
    }
}

// ---------------------------------------------------------------- LayerNorm(DV=128) + gate -> bf16
__global__ __launch_bounds__(256) void ln_gate_kernel(
    const float* __restrict__ ob, const float* __restrict__ g,
    const float* __restrict__ lnw, const float* __restrict__ lnb,
    __hip_bfloat16* __restrict__ opr)
{
    int row = blockIdx.x * 4 + (threadIdx.x >> 6);
    int lane = threadIdx.x & 63;
    size_t base = (size_t)row * 128 + lane * 2;
    float2 xv = *(const float2*)(ob + base);
    float s = xv.x + xv.y;
#pragma unroll
    for (int m = 1; m <= 32; m <<= 1) s += __shfl_xor(s, m);
    float mean = s * (1.0f / 128.0f);
    float d0 = xv.x - mean, d1 = xv.y - mean;
    float vs = d0 * d0 + d1 * d1;
#pragma unroll
    for (int m = 1; m <= 32; m <<= 1) vs += __shfl_xor(vs, m);
    float rstd = rsqrtf(vs * (1.0f / 128.0f) + 1e-5f);
    float2 gv = *(const float2*)(g + base);
    float w0 = lnw[lane * 2], w1 = lnw[lane * 2 + 1];
    float b0 = lnb[lane * 2], b1 = lnb[lane * 2 + 1];
    opr[base] = __float2bfloat16((d0 * rstd * w0 + b0) * gv.x);
    opr[base + 1] = __float2bfloat16((d1 * rstd * w1 + b1) * gv.y);
}

// ---------------------------------------------------------------- launch
extern "C" void kernel_launch(void* const* d_in, const int* in_sizes, int n_in,
                              void* d_out, int out_size, void* d_ws, size_t ws_size,
                              hipStream_t stream)
{
    const float* x    = (const float*)d_in[0];
    const float* Wq   = (const float*)d_in[1];
    const float* Wk   = (const float*)d_in[2];
    const float* Wv   = (const float*)d_in[3];
    const float* Wa   = (const float*)d_in[4];
    const float* ba   = (const float*)d_in[5];
    const float* Wb   = (const float*)d_in[6];
    const float* bb   = (const float*)d_in[7];
    const float* Wg   = (const float*)d_in[8];
    const float* Wo   = (const float*)d_in[9];
    const float* qc_w = (const float*)d_in[10];
    const float* qc_b = (const float*)d_in[11];
    const float* kc_w = (const float*)d_in[12];
    const float* kc_b = (const float*)d_in[13];
    const float* vc_w = (const float*)d_in[14];
    const float* vc_b = (const float*)d_in[15];
    const float* ln_w = (const float*)d_in[16];
    const float* ln_b = (const float*)d_in[17];
    float* out = (float*)d_out;

    char* W = (char*)d_ws;
    __hip_bfloat16* xbf  = (__hip_bfloat16*)(W + 0);            // 16777216
    __hip_bfloat16* wcat = (__hip_bfloat16*)(W + 16777216);     // 8650752
    __hip_bfloat16* wobf = (__hip_bfloat16*)(W + 25427968);     // 2097152
    float* qraw  = (float*)(W + 27525120);                      // 16777216
    float* kraw  = (float*)(W + 44302336);                      // 16777216
    float* vraw  = (float*)(W + 61079552);                      // 33554432
    float* abuf  = (float*)(W + 94633984);                      // 33554432
    float* betab = (float*)(W + 128188416);                     // 262144
    float* gbuf  = (float*)(W + 128450560);                     // 33554432
    float* kcb   = (float*)(W + 162004992);                     // 16777216
    float* vcb   = (float*)(W + 178782208);                     // 33554432
    float* qcb   = (float*)xbf;                 // reuse: xbf dead after gemm1
    float* obuf  = (float*)qraw;                // reuse: qraw+kraw dead after convs
    __hip_bfloat16* opr = (__hip_bfloat16*)vraw;// reuse: vraw dead after conv-v

    pack_f32_bf16_kernel<<<8192, 256, 0, stream>>>(x, xbf, 2097152);
    pack_w_kernel<<<16896, 256, 0, stream>>>(Wq, Wk, Wv, Wa, Wb, Wg, wcat);
    pack_f32_bf16_kernel<<<1024, 256, 0, stream>>>(Wo, wobf, 262144);
    gemm1_kernel<<<dim3(64, 33), 256, 0, stream>>>(xbf, wcat, qraw, kraw, vraw,
                                                   abuf, betab, gbuf, ba, bb);
    conv_silu_kernel<<<16384, 256, 0, stream>>>(qraw, qc_w, qc_b, qcb, 512, 4194304, 1.0f);
    conv_silu_kernel<<<16384, 256, 0, stream>>>(kraw, kc_w, kc_b, kcb, 512, 4194304, 0.125f);
    conv_silu_kernel<<<32768, 256, 0, stream>>>(vraw, vc_w, vc_b, vcb, 1024, 8388608, 1.0f);
    scan_kernel<<<128, 64, 0, stream>>>(qcb, kcb, vcb, abuf, betab, obuf);
    ln_gate_kernel<<<16384, 256, 0, stream>>>(obuf, gbuf, ln_w, ln_b, opr);
    gemm2_kernel<<<dim3(64, 8), 256, 0, stream>>>(opr, wobf, out);
}

// Round 3
// 1361.891 us; speedup vs baseline: 1.5123x; 1.5123x over previous
//
#include <hip/hip_runtime.h>
#include <hip/hip_bf16.h>
#include <cstdint>
#include <cstddef>

#define TDIM 2048
#define NH 8

using f32x4 = __attribute__((ext_vector_type(4))) float;
using s16x8 = __attribute__((ext_vector_type(8))) short;

__device__ __forceinline__ float sigm(float x) { return 1.0f / (1.0f + __expf(-x)); }

#define GLDS(gp, lp)                                                          \
    __builtin_amdgcn_global_load_lds(                                         \
        (const __attribute__((address_space(1))) void*)(gp),                  \
        (__attribute__((address_space(3))) void*)(lp), 16, 0, 0)

// DPP-based 8-lane reduction (lanes grouped by low 3 bits).
template<int CTRL>
__device__ __forceinline__ float dpp_add(float x) {
    int p = __builtin_amdgcn_mov_dpp(__float_as_int(x), CTRL, 0xF, 0xF, true);
    return x + __int_as_float(p);
}
__device__ __forceinline__ float reduce8(float x) {
    x = dpp_add<0xB1>(x);   // quad_perm [1,0,3,2]  = xor1
    x = dpp_add<0x4E>(x);   // quad_perm [2,3,0,1]  = xor2
    x = dpp_add<0x141>(x);  // row_half_mirror      = xor7 within 8 (cross-quad)
    return x;
}

// ---------------------------------------------------------------- pack kernels
__global__ __launch_bounds__(256) void pack_f32_bf16_kernel(
    const float* __restrict__ src, __hip_bfloat16* __restrict__ dst, int n4)
{
    int i = blockIdx.x * 256 + threadIdx.x;
    if (i >= n4) return;
    float4 v = *(const float4*)(src + (size_t)i * 4);
    size_t o = (size_t)i * 4;
    dst[o + 0] = __float2bfloat16(v.x);
    dst[o + 1] = __float2bfloat16(v.y);
    dst[o + 2] = __float2bfloat16(v.z);
    dst[o + 3] = __float2bfloat16(v.w);
}

__global__ __launch_bounds__(256) void pack_w_kernel(
    const float* __restrict__ Wq, const float* __restrict__ Wk,
    const float* __restrict__ Wv, const float* __restrict__ Wa,
    const float* __restrict__ Wb, const float* __restrict__ Wg,
    __hip_bfloat16* __restrict__ dst)
{
    int e = blockIdx.x * 256 + threadIdx.x;  // < 4224*1024
    int r = e >> 10, c = e & 1023;
    float vv;
    if      (r <  512) vv = Wq[(size_t)r * 1024 + c];
    else if (r < 1024) vv = Wk[(size_t)(r -  512) * 1024 + c];
    else if (r < 2048) vv = Wv[(size_t)(r - 1024) * 1024 + c];
    else if (r < 3072) vv = Wa[(size_t)(r - 2048) * 1024 + c];
    else if (r < 3080) vv = Wb[(size_t)(r - 3072) * 1024 + c];
    else if (r < 4104) vv = Wg[(size_t)(r - 3080) * 1024 + c];
    else               vv = 0.0f;
    dst[e] = __float2bfloat16(vv);
}

// ---------------------------------------------------------------- GEMM 1 (fused epilogue)
__global__ __launch_bounds__(256) void gemm1_kernel(
    const __hip_bfloat16* __restrict__ A, const __hip_bfloat16* __restrict__ Bw,
    float* __restrict__ qraw, float* __restrict__ kraw, float* __restrict__ vraw,
    float* __restrict__ abuf, float* __restrict__ betab, float* __restrict__ gbuf,
    const float* __restrict__ ba, const float* __restrict__ bb)
{
    constexpr int Kd = 1024;
    __shared__ __attribute__((aligned(16))) __hip_bfloat16 At[128 * 32];
    __shared__ __attribute__((aligned(16))) __hip_bfloat16 Bt[128 * 32];
    const int tid = threadIdx.x;
    const int mBase = blockIdx.x * 128;
    const int nBase = blockIdx.y * 128;
    const int wave = tid >> 6, lane = tid & 63;
    const int wm = (wave >> 1) * 64, wn = (wave & 1) * 64;
    const int quad = lane >> 4, l16 = lane & 15;

    f32x4 acc[4][4];
    for (int i = 0; i < 4; i++)
        for (int j = 0; j < 4; j++)
            for (int r = 0; r < 4; r++) acc[i][j][r] = 0.0f;

    const int srow = tid >> 2;
    const int skk = (tid & 3) * 8;
    const __hip_bfloat16* Ag = A + (size_t)(mBase + srow) * Kd + skk;
    const __hip_bfloat16* Bg = Bw + (size_t)(nBase + srow) * Kd + skk;
    __hip_bfloat16* Al = &At[srow * 32 + skk];
    __hip_bfloat16* Bl = &Bt[srow * 32 + skk];

    for (int k0 = 0; k0 < Kd; k0 += 32) {
        GLDS(Ag + k0, Al);
        GLDS(Ag + k0 + (size_t)64 * Kd, Al + 64 * 32);
        GLDS(Bg + k0, Bl);
        GLDS(Bg + k0 + (size_t)64 * Kd, Bl + 64 * 32);
        __syncthreads();
        s16x8 af[4], bfr[4];
#pragma unroll
        for (int i = 0; i < 4; i++)
            af[i] = *(const s16x8*)&At[(wm + i * 16 + l16) * 32 + quad * 8];
#pragma unroll
        for (int j = 0; j < 4; j++)
            bfr[j] = *(const s16x8*)&Bt[(wn + j * 16 + l16) * 32 + quad * 8];
#pragma unroll
        for (int i = 0; i < 4; i++)
#pragma unroll
            for (int j = 0; j < 4; j++)
                acc[i][j] = __builtin_amdgcn_mfma_f32_16x16x32_bf16(af[i], bfr[j], acc[i][j], 0, 0, 0);
        __syncthreads();
    }

    for (int j = 0; j < 4; j++) {
        int n = nBase + wn + j * 16 + l16;
        for (int i = 0; i < 4; i++) {
            for (int r = 0; r < 4; r++) {
                int m = mBase + wm + i * 16 + quad * 4 + r;
                float val = acc[i][j][r];
                if (n < 512) qraw[(size_t)m * 512 + n] = val;
                else if (n < 1024) kraw[(size_t)m * 512 + n - 512] = val;
                else if (n < 2048) vraw[(size_t)m * 1024 + n - 1024] = val;
                else if (n < 3072) abuf[(size_t)m * 1024 + n - 2048] = sigm(val + ba[n - 2048]);
                else if (n < 3080) betab[(size_t)m * 8 + n - 3072] = sigm(val + bb[n - 3072]);
                else if (n < 4104) gbuf[(size_t)m * 1024 + n - 3080] = sigm(val);
            }
        }
    }
}

// ---------------------------------------------------------------- GEMM 2 (plain)
__global__ __launch_bounds__(256) void gemm2_kernel(
    const __hip_bfloat16* __restrict__ A, const __hip_bfloat16* __restrict__ Bw,
    float* __restrict__ out)
{
    constexpr int Kd = 1024;
    __shared__ __attribute__((aligned(16))) __hip_bfloat16 At[128 * 32];
    __shared__ __attribute__((aligned(16))) __hip_bfloat16 Bt[128 * 32];
    const int tid = threadIdx.x;
    const int mBase = blockIdx.x * 128;
    const int nBase = blockIdx.y * 128;
    const int wave = tid >> 6, lane = tid & 63;
    const int wm = (wave >> 1) * 64, wn = (wave & 1) * 64;
    const int quad = lane >> 4, l16 = lane & 15;

    f32x4 acc[4][4];
    for (int i = 0; i < 4; i++)
        for (int j = 0; j < 4; j++)
            for (int r = 0; r < 4; r++) acc[i][j][r] = 0.0f;

    const int srow = tid >> 2;
    const int skk = (tid & 3) * 8;
    const __hip_bfloat16* Ag = A + (size_t)(mBase + srow) * Kd + skk;
    const __hip_bfloat16* Bg = Bw + (size_t)(nBase + srow) * Kd + skk;
    __hip_bfloat16* Al = &At[srow * 32 + skk];
    __hip_bfloat16* Bl = &Bt[srow * 32 + skk];

    for (int k0 = 0; k0 < Kd; k0 += 32) {
        GLDS(Ag + k0, Al);
        GLDS(Ag + k0 + (size_t)64 * Kd, Al + 64 * 32);
        GLDS(Bg + k0, Bl);
        GLDS(Bg + k0 + (size_t)64 * Kd, Bl + 64 * 32);
        __syncthreads();
        s16x8 af[4], bfr[4];
#pragma unroll
        for (int i = 0; i < 4; i++)
            af[i] = *(const s16x8*)&At[(wm + i * 16 + l16) * 32 + quad * 8];
#pragma unroll
        for (int j = 0; j < 4; j++)
            bfr[j] = *(const s16x8*)&Bt[(wn + j * 16 + l16) * 32 + quad * 8];
#pragma unroll
        for (int i = 0; i < 4; i++)
#pragma unroll
            for (int j = 0; j < 4; j++)
                acc[i][j] = __builtin_amdgcn_mfma_f32_16x16x32_bf16(af[i], bfr[j], acc[i][j], 0, 0, 0);
        __syncthreads();
    }

    for (int j = 0; j < 4; j++) {
        int n = nBase + wn + j * 16 + l16;
        for (int i = 0; i < 4; i++) {
            for (int r = 0; r < 4; r++) {
                int m = mBase + wm + i * 16 + quad * 4 + r;
                out[(size_t)m * 1024 + n] = acc[i][j][r];
            }
        }
    }
}

// ---------------------------------------------------------------- depthwise causal conv (K=4) + SiLU
__global__ __launch_bounds__(256) void conv_silu_kernel(
    const float* __restrict__ src, const float* __restrict__ w4,
    const float* __restrict__ bias, float* __restrict__ dst,
    int C, int total, float scale)
{
    int e = blockIdx.x * 256 + threadIdx.x;
    if (e >= total) return;
    int c = e % C;
    int bt = e / C;
    int t = bt % TDIM;
    const float* wc = w4 + (size_t)c * 4;
    const float* s = src + (size_t)bt * C + c;
    float acc = bias[c];
    acc = fmaf(s[0], wc[3], acc);
    if (t >= 1) acc = fmaf(s[-C], wc[2], acc);
    if (t >= 2) acc = fmaf(s[-2 * C], wc[1], acc);
    if (t >= 3) acc = fmaf(s[-3 * C], wc[0], acc);
    dst[e] = acc * sigm(acc) * scale;
}

// ---------------------------------------------------------------- gated delta-rule scan v3
// 512 blocks x 64 threads; block -> (b, h, vg of 8 columns).
// lane = vi*8 + ks: ks (LOW 3 bits) indexes 8 k-slices, vi indexes 8 v-cols.
// Lane state: S[ks*8..ks*8+8)[v]. 8-lane reductions via DPP (VALU pipe),
// loads prefetched 3 steps ahead (4 buffers) to cover L2/L3 latency.
#define SCAN_LOAD(K0, K1, Q0, Q1, VV, AA, BB, TT) do {                        \
    size_t ko = kqBase + (size_t)(TT) * 512;                                  \
    K0 = *(const float4*)(kc + ko); K1 = *(const float4*)(kc + ko + 4);       \
    Q0 = *(const float4*)(qc + ko); Q1 = *(const float4*)(qc + ko + 4);       \
    size_t vo = vaBase + (size_t)(TT) * 1024;                                 \
    VV = vc[vo]; AA = ab[vo]; BB = betab[beBase + (size_t)(TT) * 8];          \
} while (0)

#define SCAN_STEP(K0, K1, Q0, Q1, VV, AA, BB, TT) do {                        \
    float r0 = K0.x * S0, r1 = K0.y * S1;                                     \
    r0 = fmaf(K0.z, S2, r0); r1 = fmaf(K0.w, S3, r1);                         \
    r0 = fmaf(K1.x, S4, r0); r1 = fmaf(K1.y, S5, r1);                         \
    r0 = fmaf(K1.z, S6, r0); r1 = fmaf(K1.w, S7, r1);                         \
    float rr = reduce8(r0 + r1);                                              \
    float cc = BB * (rr - VV);                                                \
    float o0, o1;                                                             \
    S0 = fmaf(-cc, K0.x, AA * S0); o0 = Q0.x * S0;                            \
    S1 = fmaf(-cc, K0.y, AA * S1); o1 = Q0.y * S1;                            \
    S2 = fmaf(-cc, K0.z, AA * S2); o0 = fmaf(Q0.z, S2, o0);                   \
    S3 = fmaf(-cc, K0.w, AA * S3); o1 = fmaf(Q0.w, S3, o1);                   \
    S4 = fmaf(-cc, K1.x, AA * S4); o0 = fmaf(Q1.x, S4, o0);                   \
    S5 = fmaf(-cc, K1.y, AA * S5); o1 = fmaf(Q1.y, S5, o1);                   \
    S6 = fmaf(-cc, K1.z, AA * S6); o0 = fmaf(Q1.z, S6, o0);                   \
    S7 = fmaf(-cc, K1.w, AA * S7); o1 = fmaf(Q1.w, S7, o1);                   \
    float oo = reduce8(o0 + o1);                                              \
    if (ks == 0) ob[vaBase + (size_t)(TT) * 1024] = oo;                       \
} while (0)

#define WRAPT(X) ((X) < TDIM ? (X) : 0)

__global__ __launch_bounds__(64) void scan_kernel(
    const float* __restrict__ qc, const float* __restrict__ kc,
    const float* __restrict__ vc, const float* __restrict__ ab,
    const float* __restrict__ betab, float* __restrict__ ob)
{
    const int bid = blockIdx.x;
    const int vg = bid & 15, h = (bid >> 4) & 7, b = bid >> 7;
    const int lane = threadIdx.x;
    const int ks = lane & 7, vi = lane >> 3;
    const int v = vg * 8 + vi;
    float S0 = 0, S1 = 0, S2 = 0, S3 = 0, S4 = 0, S5 = 0, S6 = 0, S7 = 0;
    const size_t kqBase = ((size_t)b * TDIM * NH + h) * 64 + (size_t)ks * 8;  // +t*512
    const size_t vaBase = ((size_t)b * TDIM * NH + h) * 128 + v;              // +t*1024
    const size_t beBase = (size_t)b * TDIM * 8 + h;                           // +t*8

    float4 kA0, kA1, qA0, qA1; float vA, aA, bA;
    float4 kB0, kB1, qB0, qB1; float vB, aB, bB;
    float4 kC0, kC1, qC0, qC1; float vC, aC, bC;
    float4 kD0, kD1, qD0, qD1; float vD, aD, bD;
    SCAN_LOAD(kA0, kA1, qA0, qA1, vA, aA, bA, 0);
    SCAN_LOAD(kB0, kB1, qB0, qB1, vB, aB, bB, 1);
    SCAN_LOAD(kC0, kC1, qC0, qC1, vC, aC, bC, 2);
    for (int t = 0; t < TDIM; t += 4) {
        SCAN_LOAD(kD0, kD1, qD0, qD1, vD, aD, bD, t + 3);
        SCAN_STEP(kA0, kA1, qA0, qA1, vA, aA, bA, t);
        SCAN_LOAD(kA0, kA1, qA0, qA1, vA, aA, bA, WRAPT(t + 4));
        SCAN_STEP(kB0, kB1, qB0, qB1, vB, aB, bB, t + 1);
        SCAN_LOAD(kB0, kB1, qB0, qB1, vB, aB, bB, WRAPT(t + 5));
        SCAN_STEP(kC0, kC1, qC0, qC1, vC, aC, bC, t + 2);
        SCAN_LOAD(kC0, kC1, qC0, qC1, vC, aC, bC, WRAPT(t + 6));
        SCAN_STEP(kD0, kD1, qD0, qD1, vD, aD, bD, t + 3);
    }
}

// ---------------------------------------------------------------- LayerNorm(DV=128) + gate -> bf16
__global__ __launch_bounds__(256) void ln_gate_kernel(
    const float* __restrict__ ob, const float* __restrict__ g,
    const float* __restrict__ lnw, const float* __restrict__ lnb,
    __hip_bfloat16* __restrict__ opr)
{
    int row = blockIdx.x * 4 + (threadIdx.x >> 6);
    int lane = threadIdx.x & 63;
    size_t base = (size_t)row * 128 + lane * 2;
    float2 xv = *(const float2*)(ob + base);
    float s = xv.x + xv.y;
#pragma unroll
    for (int m = 1; m <= 32; m <<= 1) s += __shfl_xor(s, m);
    float mean = s * (1.0f / 128.0f);
    float d0 = xv.x - mean, d1 = xv.y - mean;
    float vs = d0 * d0 + d1 * d1;
#pragma unroll
    for (int m = 1; m <= 32; m <<= 1) vs += __shfl_xor(vs, m);
    float rstd = rsqrtf(vs * (1.0f / 128.0f) + 1e-5f);
    float2 gv = *(const float2*)(g + base);
    float w0 = lnw[lane * 2], w1 = lnw[lane * 2 + 1];
    float b0 = lnb[lane * 2], b1 = lnb[lane * 2 + 1];
    opr[base] = __float2bfloat16((d0 * rstd * w0 + b0) * gv.x);
    opr[base + 1] = __float2bfloat16((d1 * rstd * w1 + b1) * gv.y);
}

// ---------------------------------------------------------------- launch
extern "C" void kernel_launch(void* const* d_in, const int* in_sizes, int n_in,
                              void* d_out, int out_size, void* d_ws, size_t ws_size,
                              hipStream_t stream)
{
    const float* x    = (const float*)d_in[0];
    const float* Wq   = (const float*)d_in[1];
    const float* Wk   = (const float*)d_in[2];
    const float* Wv   = (const float*)d_in[3];
    const float* Wa   = (const float*)d_in[4];
    const float* ba   = (const float*)d_in[5];
    const float* Wb   = (const float*)d_in[6];
    const float* bb   = (const float*)d_in[7];
    const float* Wg   = (const float*)d_in[8];
    const float* Wo   = (const float*)d_in[9];
    const float* qc_w = (const float*)d_in[10];
    const float* qc_b = (const float*)d_in[11];
    const float* kc_w = (const float*)d_in[12];
    const float* kc_b = (const float*)d_in[13];
    const float* vc_w = (const float*)d_in[14];
    const float* vc_b = (const float*)d_in[15];
    const float* ln_w = (const float*)d_in[16];
    const float* ln_b = (const float*)d_in[17];
    float* out = (float*)d_out;

    char* W = (char*)d_ws;
    __hip_bfloat16* xbf  = (__hip_bfloat16*)(W + 0);            // 16777216
    __hip_bfloat16* wcat = (__hip_bfloat16*)(W + 16777216);     // 8650752
    __hip_bfloat16* wobf = (__hip_bfloat16*)(W + 25427968);     // 2097152
    float* qraw  = (float*)(W + 27525120);                      // 16777216
    float* kraw  = (float*)(W + 44302336);                      // 16777216
    float* vraw  = (float*)(W + 61079552);                      // 33554432
    float* abuf  = (float*)(W + 94633984);                      // 33554432
    float* betab = (float*)(W + 128188416);                     // 262144
    float* gbuf  = (float*)(W + 128450560);                     // 33554432
    float* kcb   = (float*)(W + 162004992);                     // 16777216
    float* vcb   = (float*)(W + 178782208);                     // 33554432
    float* qcb   = (float*)xbf;                 // reuse: xbf dead after gemm1
    float* obuf  = (float*)qraw;                // reuse: qraw+kraw dead after convs
    __hip_bfloat16* opr = (__hip_bfloat16*)vraw;// reuse: vraw dead after conv-v

    pack_f32_bf16_kernel<<<8192, 256, 0, stream>>>(x, xbf, 2097152);
    pack_w_kernel<<<16896, 256, 0, stream>>>(Wq, Wk, Wv, Wa, Wb, Wg, wcat);
    pack_f32_bf16_kernel<<<1024, 256, 0, stream>>>(Wo, wobf, 262144);
    gemm1_kernel<<<dim3(64, 33), 256, 0, stream>>>(xbf, wcat, qraw, kraw, vraw,
                                                   abuf, betab, gbuf, ba, bb);
    conv_silu_kernel<<<16384, 256, 0, stream>>>(qraw, qc_w, qc_b, qcb, 512, 4194304, 1.0f);
    conv_silu_kernel<<<16384, 256, 0, stream>>>(kraw, kc_w, kc_b, kcb, 512, 4194304, 0.125f);
    conv_silu_kernel<<<32768, 256, 0, stream>>>(vraw, vc_w, vc_b, vcb, 1024, 8388608, 1.0f);
    scan_kernel<<<512, 64, 0, stream>>>(qcb, kcb, vcb, abuf, betab, obuf);
    ln_gate_kernel<<<16384, 256, 0, stream>>>(obuf, gbuf, ln_w, ln_b, opr);
    gemm2_kernel<<<dim3(64, 8), 256, 0, stream>>>(opr, wobf, out);
}

// Round 4
// 816.558 us; speedup vs baseline: 2.5222x; 1.6678x over previous
//
#include <hip/hip_runtime.h>
#include <hip/hip_bf16.h>
#include <cstdint>
#include <cstddef>

#define TDIM 2048
#define NH 8

using f32x4 = __attribute__((ext_vector_type(4))) float;
using s16x8 = __attribute__((ext_vector_type(8))) short;

__device__ __forceinline__ float sigm(float x) { return 1.0f / (1.0f + __expf(-x)); }

#define GLDS(gp, lp)                                                          \
    __builtin_amdgcn_global_load_lds(                                         \
        (const __attribute__((address_space(1))) void*)(gp),                  \
        (__attribute__((address_space(3))) void*)(lp), 16, 0, 0)

// DPP-based 8-lane reduction (lanes grouped by low 3 bits).
template<int CTRL>
__device__ __forceinline__ float dpp_add(float x) {
    int p = __builtin_amdgcn_mov_dpp(__float_as_int(x), CTRL, 0xF, 0xF, true);
    return x + __int_as_float(p);
}
__device__ __forceinline__ float reduce8(float x) {
    x = dpp_add<0xB1>(x);   // quad_perm [1,0,3,2]  = xor1
    x = dpp_add<0x4E>(x);   // quad_perm [2,3,0,1]  = xor2
    x = dpp_add<0x141>(x);  // row_half_mirror      = xor7 within 8 (cross-quad)
    return x;
}

// ---------------------------------------------------------------- pack kernels
__global__ __launch_bounds__(256) void pack_f32_bf16_kernel(
    const float* __restrict__ src, __hip_bfloat16* __restrict__ dst, int n4)
{
    int i = blockIdx.x * 256 + threadIdx.x;
    if (i >= n4) return;
    float4 v = *(const float4*)(src + (size_t)i * 4);
    size_t o = (size_t)i * 4;
    dst[o + 0] = __float2bfloat16(v.x);
    dst[o + 1] = __float2bfloat16(v.y);
    dst[o + 2] = __float2bfloat16(v.z);
    dst[o + 3] = __float2bfloat16(v.w);
}

__global__ __launch_bounds__(256) void pack_w_kernel(
    const float* __restrict__ Wq, const float* __restrict__ Wk,
    const float* __restrict__ Wv, const float* __restrict__ Wa,
    const float* __restrict__ Wb, const float* __restrict__ Wg,
    __hip_bfloat16* __restrict__ dst)
{
    int e = blockIdx.x * 256 + threadIdx.x;  // < 4224*1024
    int r = e >> 10, c = e & 1023;
    float vv;
    if      (r <  512) vv = Wq[(size_t)r * 1024 + c];
    else if (r < 1024) vv = Wk[(size_t)(r -  512) * 1024 + c];
    else if (r < 2048) vv = Wv[(size_t)(r - 1024) * 1024 + c];
    else if (r < 3072) vv = Wa[(size_t)(r - 2048) * 1024 + c];
    else if (r < 3080) vv = Wb[(size_t)(r - 3072) * 1024 + c];
    else if (r < 4104) vv = Wg[(size_t)(r - 3080) * 1024 + c];
    else               vv = 0.0f;
    dst[e] = __float2bfloat16(vv);
}

// ---------------------------------------------------------------- GEMM 1 (fused epilogue, coalesced stores)
__global__ __launch_bounds__(256) void gemm1_kernel(
    const __hip_bfloat16* __restrict__ A, const __hip_bfloat16* __restrict__ Bw,
    float* __restrict__ qraw, float* __restrict__ kraw, float* __restrict__ vraw,
    float* __restrict__ abuf, float* __restrict__ betab, float* __restrict__ gbuf,
    const float* __restrict__ ba, const float* __restrict__ bb)
{
    constexpr int Kd = 1024;
    __shared__ __attribute__((aligned(16))) __hip_bfloat16 At[128 * 32];
    __shared__ __attribute__((aligned(16))) __hip_bfloat16 Bt[128 * 32];
    __shared__ __attribute__((aligned(16))) float Ct[4][16 * 68];  // per-wave transpose scratch
    const int tid = threadIdx.x;
    const int mBase = blockIdx.x * 128;
    const int nBase = blockIdx.y * 128;
    const int wave = tid >> 6, lane = tid & 63;
    const int wm = (wave >> 1) * 64, wn = (wave & 1) * 64;
    const int quad = lane >> 4, l16 = lane & 15;

    f32x4 acc[4][4];
    for (int i = 0; i < 4; i++)
        for (int j = 0; j < 4; j++)
            for (int r = 0; r < 4; r++) acc[i][j][r] = 0.0f;

    const int srow = tid >> 2;
    const int skk = (tid & 3) * 8;
    const __hip_bfloat16* Ag = A + (size_t)(mBase + srow) * Kd + skk;
    const __hip_bfloat16* Bg = Bw + (size_t)(nBase + srow) * Kd + skk;
    __hip_bfloat16* Al = &At[srow * 32 + skk];
    __hip_bfloat16* Bl = &Bt[srow * 32 + skk];

    for (int k0 = 0; k0 < Kd; k0 += 32) {
        GLDS(Ag + k0, Al);
        GLDS(Ag + k0 + (size_t)64 * Kd, Al + 64 * 32);
        GLDS(Bg + k0, Bl);
        GLDS(Bg + k0 + (size_t)64 * Kd, Bl + 64 * 32);
        __syncthreads();
        s16x8 af[4], bfr[4];
#pragma unroll
        for (int i = 0; i < 4; i++)
            af[i] = *(const s16x8*)&At[(wm + i * 16 + l16) * 32 + quad * 8];
#pragma unroll
        for (int j = 0; j < 4; j++)
            bfr[j] = *(const s16x8*)&Bt[(wn + j * 16 + l16) * 32 + quad * 8];
#pragma unroll
        for (int i = 0; i < 4; i++)
#pragma unroll
            for (int j = 0; j < 4; j++)
                acc[i][j] = __builtin_amdgcn_mfma_f32_16x16x32_bf16(af[i], bfr[j], acc[i][j], 0, 0, 0);
        __syncthreads();
    }

    // ---- epilogue: LDS transpose -> per-lane float4 coalesced stores ----
    // Lane owns 4 consecutive output columns ncol..ncol+3 (never straddles a
    // region boundary: all boundaries are multiples of 4). Routing is a
    // per-lane constant: {base, row-stride, sigmoid?, bias}.
    const int ncol = nBase + wn + l16 * 4;
    float* basep; size_t rstr; bool dosig = false; bool skip = false;
    float4 bias = make_float4(0.f, 0.f, 0.f, 0.f);
    if (ncol < 512)       { basep = qraw + ncol;          rstr = 512;  }
    else if (ncol < 1024) { basep = kraw + (ncol - 512);  rstr = 512;  }
    else if (ncol < 2048) { basep = vraw + (ncol - 1024); rstr = 1024; }
    else if (ncol < 3072) { basep = abuf + (ncol - 2048); rstr = 1024; dosig = true;
                            bias = *(const float4*)(ba + (ncol - 2048)); }
    else if (ncol < 3080) { basep = betab + (ncol - 3072); rstr = 8;   dosig = true;
                            bias = *(const float4*)(bb + (ncol - 3072)); }
    else if (ncol < 4104) { basep = gbuf + (ncol - 3080); rstr = 1024; dosig = true; }
    else                  { basep = gbuf; rstr = 0; skip = true; }

#pragma unroll
    for (int i = 0; i < 4; i++) {
#pragma unroll
        for (int j = 0; j < 4; j++)
#pragma unroll
            for (int r = 0; r < 4; r++)
                Ct[wave][(quad * 4 + r) * 68 + j * 16 + l16] = acc[i][j][r];
        __syncthreads();
#pragma unroll
        for (int p = 0; p < 4; p++) {
            int rr = p * 4 + quad;
            float4 val = *(const float4*)&Ct[wave][rr * 68 + l16 * 4];
            if (dosig) {
                val.x = sigm(val.x + bias.x);
                val.y = sigm(val.y + bias.y);
                val.z = sigm(val.z + bias.z);
                val.w = sigm(val.w + bias.w);
            }
            int m = mBase + wm + i * 16 + rr;
            if (!skip) *(float4*)(basep + (size_t)m * rstr) = val;
        }
        __syncthreads();
    }
}

// ---------------------------------------------------------------- GEMM 2 (plain, coalesced stores)
__global__ __launch_bounds__(256) void gemm2_kernel(
    const __hip_bfloat16* __restrict__ A, const __hip_bfloat16* __restrict__ Bw,
    float* __restrict__ out)
{
    constexpr int Kd = 1024;
    __shared__ __attribute__((aligned(16))) __hip_bfloat16 At[128 * 32];
    __shared__ __attribute__((aligned(16))) __hip_bfloat16 Bt[128 * 32];
    __shared__ __attribute__((aligned(16))) float Ct[4][16 * 68];
    const int tid = threadIdx.x;
    const int mBase = blockIdx.x * 128;
    const int nBase = blockIdx.y * 128;
    const int wave = tid >> 6, lane = tid & 63;
    const int wm = (wave >> 1) * 64, wn = (wave & 1) * 64;
    const int quad = lane >> 4, l16 = lane & 15;

    f32x4 acc[4][4];
    for (int i = 0; i < 4; i++)
        for (int j = 0; j < 4; j++)
            for (int r = 0; r < 4; r++) acc[i][j][r] = 0.0f;

    const int srow = tid >> 2;
    const int skk = (tid & 3) * 8;
    const __hip_bfloat16* Ag = A + (size_t)(mBase + srow) * Kd + skk;
    const __hip_bfloat16* Bg = Bw + (size_t)(nBase + srow) * Kd + skk;
    __hip_bfloat16* Al = &At[srow * 32 + skk];
    __hip_bfloat16* Bl = &Bt[srow * 32 + skk];

    for (int k0 = 0; k0 < Kd; k0 += 32) {
        GLDS(Ag + k0, Al);
        GLDS(Ag + k0 + (size_t)64 * Kd, Al + 64 * 32);
        GLDS(Bg + k0, Bl);
        GLDS(Bg + k0 + (size_t)64 * Kd, Bl + 64 * 32);
        __syncthreads();
        s16x8 af[4], bfr[4];
#pragma unroll
        for (int i = 0; i < 4; i++)
            af[i] = *(const s16x8*)&At[(wm + i * 16 + l16) * 32 + quad * 8];
#pragma unroll
        for (int j = 0; j < 4; j++)
            bfr[j] = *(const s16x8*)&Bt[(wn + j * 16 + l16) * 32 + quad * 8];
#pragma unroll
        for (int i = 0; i < 4; i++)
#pragma unroll
            for (int j = 0; j < 4; j++)
                acc[i][j] = __builtin_amdgcn_mfma_f32_16x16x32_bf16(af[i], bfr[j], acc[i][j], 0, 0, 0);
        __syncthreads();
    }

    const int ncol = nBase + wn + l16 * 4;
    float* basep = out + ncol;
#pragma unroll
    for (int i = 0; i < 4; i++) {
#pragma unroll
        for (int j = 0; j < 4; j++)
#pragma unroll
            for (int r = 0; r < 4; r++)
                Ct[wave][(quad * 4 + r) * 68 + j * 16 + l16] = acc[i][j][r];
        __syncthreads();
#pragma unroll
        for (int p = 0; p < 4; p++) {
            int rr = p * 4 + quad;
            float4 val = *(const float4*)&Ct[wave][rr * 68 + l16 * 4];
            int m = mBase + wm + i * 16 + rr;
            *(float4*)(basep + (size_t)m * 1024) = val;
        }
        __syncthreads();
    }
}

// ---------------------------------------------------------------- depthwise causal conv (K=4) + SiLU
__global__ __launch_bounds__(256) void conv_silu_kernel(
    const float* __restrict__ src, const float* __restrict__ w4,
    const float* __restrict__ bias, float* __restrict__ dst,
    int C, int total, float scale)
{
    int e = blockIdx.x * 256 + threadIdx.x;
    if (e >= total) return;
    int c = e % C;
    int bt = e / C;
    int t = bt % TDIM;
    const float* wc = w4 + (size_t)c * 4;
    const float* s = src + (size_t)bt * C + c;
    float acc = bias[c];
    acc = fmaf(s[0], wc[3], acc);
    if (t >= 1) acc = fmaf(s[-C], wc[2], acc);
    if (t >= 2) acc = fmaf(s[-2 * C], wc[1], acc);
    if (t >= 3) acc = fmaf(s[-3 * C], wc[0], acc);
    dst[e] = acc * sigm(acc) * scale;
}

// ---------------------------------------------------------------- gated delta-rule scan v3
#define SCAN_LOAD(K0, K1, Q0, Q1, VV, AA, BB, TT) do {                        \
    size_t ko = kqBase + (size_t)(TT) * 512;                                  \
    K0 = *(const float4*)(kc + ko); K1 = *(const float4*)(kc + ko + 4);       \
    Q0 = *(const float4*)(qc + ko); Q1 = *(const float4*)(qc + ko + 4);       \
    size_t vo = vaBase + (size_t)(TT) * 1024;                                 \
    VV = vc[vo]; AA = ab[vo]; BB = betab[beBase + (size_t)(TT) * 8];          \
} while (0)

#define SCAN_STEP(K0, K1, Q0, Q1, VV, AA, BB, TT) do {                        \
    float r0 = K0.x * S0, r1 = K0.y * S1;                                     \
    r0 = fmaf(K0.z, S2, r0); r1 = fmaf(K0.w, S3, r1);                         \
    r0 = fmaf(K1.x, S4, r0); r1 = fmaf(K1.y, S5, r1);                         \
    r0 = fmaf(K1.z, S6, r0); r1 = fmaf(K1.w, S7, r1);                         \
    float rr = reduce8(r0 + r1);                                              \
    float cc = BB * (rr - VV);                                                \
    float o0, o1;                                                             \
    S0 = fmaf(-cc, K0.x, AA * S0); o0 = Q0.x * S0;                            \
    S1 = fmaf(-cc, K0.y, AA * S1); o1 = Q0.y * S1;                            \
    S2 = fmaf(-cc, K0.z, AA * S2); o0 = fmaf(Q0.z, S2, o0);                   \
    S3 = fmaf(-cc, K0.w, AA * S3); o1 = fmaf(Q0.w, S3, o1);                   \
    S4 = fmaf(-cc, K1.x, AA * S4); o0 = fmaf(Q1.x, S4, o0);                   \
    S5 = fmaf(-cc, K1.y, AA * S5); o1 = fmaf(Q1.y, S5, o1);                   \
    S6 = fmaf(-cc, K1.z, AA * S6); o0 = fmaf(Q1.z, S6, o0);                   \
    S7 = fmaf(-cc, K1.w, AA * S7); o1 = fmaf(Q1.w, S7, o1);                   \
    float oo = reduce8(o0 + o1);                                              \
    if (ks == 0) ob[vaBase + (size_t)(TT) * 1024] = oo;                       \
} while (0)

#define WRAPT(X) ((X) < TDIM ? (X) : 0)

__global__ __launch_bounds__(64) void scan_kernel(
    const float* __restrict__ qc, const float* __restrict__ kc,
    const float* __restrict__ vc, const float* __restrict__ ab,
    const float* __restrict__ betab, float* __restrict__ ob)
{
    const int bid = blockIdx.x;
    const int vg = bid & 15, h = (bid >> 4) & 7, b = bid >> 7;
    const int lane = threadIdx.x;
    const int ks = lane & 7, vi = lane >> 3;
    const int v = vg * 8 + vi;
    float S0 = 0, S1 = 0, S2 = 0, S3 = 0, S4 = 0, S5 = 0, S6 = 0, S7 = 0;
    const size_t kqBase = ((size_t)b * TDIM * NH + h) * 64 + (size_t)ks * 8;  // +t*512
    const size_t vaBase = ((size_t)b * TDIM * NH + h) * 128 + v;              // +t*1024
    const size_t beBase = (size_t)b * TDIM * 8 + h;                           // +t*8

    float4 kA0, kA1, qA0, qA1; float vA, aA, bA;
    float4 kB0, kB1, qB0, qB1; float vB, aB, bB;
    float4 kC0, kC1, qC0, qC1; float vC, aC, bC;
    float4 kD0, kD1, qD0, qD1; float vD, aD, bD;
    SCAN_LOAD(kA0, kA1, qA0, qA1, vA, aA, bA, 0);
    SCAN_LOAD(kB0, kB1, qB0, qB1, vB, aB, bB, 1);
    SCAN_LOAD(kC0, kC1, qC0, qC1, vC, aC, bC, 2);
    for (int t = 0; t < TDIM; t += 4) {
        SCAN_LOAD(kD0, kD1, qD0, qD1, vD, aD, bD, t + 3);
        SCAN_STEP(kA0, kA1, qA0, qA1, vA, aA, bA, t);
        SCAN_LOAD(kA0, kA1, qA0, qA1, vA, aA, bA, WRAPT(t + 4));
        SCAN_STEP(kB0, kB1, qB0, qB1, vB, aB, bB, t + 1);
        SCAN_LOAD(kB0, kB1, qB0, qB1, vB, aB, bB, WRAPT(t + 5));
        SCAN_STEP(kC0, kC1, qC0, qC1, vC, aC, bC, t + 2);
        SCAN_LOAD(kC0, kC1, qC0, qC1, vC, aC, bC, WRAPT(t + 6));
        SCAN_STEP(kD0, kD1, qD0, qD1, vD, aD, bD, t + 3);
    }
}

// ---------------------------------------------------------------- LayerNorm(DV=128) + gate -> bf16
__global__ __launch_bounds__(256) void ln_gate_kernel(
    const float* __restrict__ ob, const float* __restrict__ g,
    const float* __restrict__ lnw, const float* __restrict__ lnb,
    __hip_bfloat16* __restrict__ opr)
{
    int row = blockIdx.x * 4 + (threadIdx.x >> 6);
    int lane = threadIdx.x & 63;
    size_t base = (size_t)row * 128 + lane * 2;
    float2 xv = *(const float2*)(ob + base);
    float s = xv.x + xv.y;
#pragma unroll
    for (int m = 1; m <= 32; m <<= 1) s += __shfl_xor(s, m);
    float mean = s * (1.0f / 128.0f);
    float d0 = xv.x - mean, d1 = xv.y - mean;
    float vs = d0 * d0 + d1 * d1;
#pragma unroll
    for (int m = 1; m <= 32; m <<= 1) vs += __shfl_xor(vs, m);
    float rstd = rsqrtf(vs * (1.0f / 128.0f) + 1e-5f);
    float2 gv = *(const float2*)(g + base);
    float w0 = lnw[lane * 2], w1 = lnw[lane * 2 + 1];
    float b0 = lnb[lane * 2], b1 = lnb[lane * 2 + 1];
    opr[base] = __float2bfloat16((d0 * rstd * w0 + b0) * gv.x);
    opr[base + 1] = __float2bfloat16((d1 * rstd * w1 + b1) * gv.y);
}

// ---------------------------------------------------------------- launch
extern "C" void kernel_launch(void* const* d_in, const int* in_sizes, int n_in,
                              void* d_out, int out_size, void* d_ws, size_t ws_size,
                              hipStream_t stream)
{
    const float* x    = (const float*)d_in[0];
    const float* Wq   = (const float*)d_in[1];
    const float* Wk   = (const float*)d_in[2];
    const float* Wv   = (const float*)d_in[3];
    const float* Wa   = (const float*)d_in[4];
    const float* ba   = (const float*)d_in[5];
    const float* Wb   = (const float*)d_in[6];
    const float* bb   = (const float*)d_in[7];
    const float* Wg   = (const float*)d_in[8];
    const float* Wo   = (const float*)d_in[9];
    const float* qc_w = (const float*)d_in[10];
    const float* qc_b = (const float*)d_in[11];
    const float* kc_w = (const float*)d_in[12];
    const float* kc_b = (const float*)d_in[13];
    const float* vc_w = (const float*)d_in[14];
    const float* vc_b = (const float*)d_in[15];
    const float* ln_w = (const float*)d_in[16];
    const float* ln_b = (const float*)d_in[17];
    float* out = (float*)d_out;

    char* W = (char*)d_ws;
    __hip_bfloat16* xbf  = (__hip_bfloat16*)(W + 0);            // 16777216
    __hip_bfloat16* wcat = (__hip_bfloat16*)(W + 16777216);     // 8650752
    __hip_bfloat16* wobf = (__hip_bfloat16*)(W + 25427968);     // 2097152
    float* qraw  = (float*)(W + 27525120);                      // 16777216
    float* kraw  = (float*)(W + 44302336);                      // 16777216
    float* vraw  = (float*)(W + 61079552);                      // 33554432
    float* abuf  = (float*)(W + 94633984);                      // 33554432
    float* betab = (float*)(W + 128188416);                     // 262144
    float* gbuf  = (float*)(W + 128450560);                     // 33554432
    float* kcb   = (float*)(W + 162004992);                     // 16777216
    float* vcb   = (float*)(W + 178782208);                     // 33554432
    float* qcb   = (float*)xbf;                 // reuse: xbf dead after gemm1
    float* obuf  = (float*)qraw;                // reuse: qraw+kraw dead after convs
    __hip_bfloat16* opr = (__hip_bfloat16*)vraw;// reuse: vraw dead after conv-v

    pack_f32_bf16_kernel<<<8192, 256, 0, stream>>>(x, xbf, 2097152);
    pack_w_kernel<<<16896, 256, 0, stream>>>(Wq, Wk, Wv, Wa, Wb, Wg, wcat);
    pack_f32_bf16_kernel<<<1024, 256, 0, stream>>>(Wo, wobf, 262144);
    gemm1_kernel<<<dim3(64, 33), 256, 0, stream>>>(xbf, wcat, qraw, kraw, vraw,
                                                   abuf, betab, gbuf, ba, bb);
    conv_silu_kernel<<<16384, 256, 0, stream>>>(qraw, qc_w, qc_b, qcb, 512, 4194304, 1.0f);
    conv_silu_kernel<<<16384, 256, 0, stream>>>(kraw, kc_w, kc_b, kcb, 512, 4194304, 0.125f);
    conv_silu_kernel<<<32768, 256, 0, stream>>>(vraw, vc_w, vc_b, vcb, 1024, 8388608, 1.0f);
    scan_kernel<<<512, 64, 0, stream>>>(qcb, kcb, vcb, abuf, betab, obuf);
    ln_gate_kernel<<<16384, 256, 0, stream>>>(obuf, gbuf, ln_w, ln_b, opr);
    gemm2_kernel<<<dim3(64, 8), 256, 0, stream>>>(opr, wobf, out);
}

// Round 5
// 798.096 us; speedup vs baseline: 2.5806x; 1.0231x over previous
//
#include <hip/hip_runtime.h>
#include <hip/hip_bf16.h>
#include <cstdint>
#include <cstddef>

#define TDIM 2048
#define NH 8

using f32x4 = __attribute__((ext_vector_type(4))) float;
using s16x8 = __attribute__((ext_vector_type(8))) short;

__device__ __forceinline__ float sigm(float x) { return 1.0f / (1.0f + __expf(-x)); }

#define GLDS(gp, lp)                                                          \
    __builtin_amdgcn_global_load_lds(                                         \
        (const __attribute__((address_space(1))) void*)(gp),                  \
        (__attribute__((address_space(3))) void*)(lp), 16, 0, 0)

// DPP-based 8-lane reduction (lanes grouped by low 3 bits).
template<int CTRL>
__device__ __forceinline__ float dpp_add(float x) {
    int p = __builtin_amdgcn_mov_dpp(__float_as_int(x), CTRL, 0xF, 0xF, true);
    return x + __int_as_float(p);
}
__device__ __forceinline__ float reduce8(float x) {
    x = dpp_add<0xB1>(x);   // quad_perm [1,0,3,2]  = xor1
    x = dpp_add<0x4E>(x);   // quad_perm [2,3,0,1]  = xor2
    x = dpp_add<0x141>(x);  // row_half_mirror      = xor7 within 8 (cross-quad)
    return x;
}

// ---------------------------------------------------------------- pack kernels
__global__ __launch_bounds__(256) void pack_f32_bf16_kernel(
    const float* __restrict__ src, __hip_bfloat16* __restrict__ dst, int n4)
{
    int i = blockIdx.x * 256 + threadIdx.x;
    if (i >= n4) return;
    float4 v = *(const float4*)(src + (size_t)i * 4);
    size_t o = (size_t)i * 4;
    dst[o + 0] = __float2bfloat16(v.x);
    dst[o + 1] = __float2bfloat16(v.y);
    dst[o + 2] = __float2bfloat16(v.z);
    dst[o + 3] = __float2bfloat16(v.w);
}

__global__ __launch_bounds__(256) void pack_w_kernel(
    const float* __restrict__ Wq, const float* __restrict__ Wk,
    const float* __restrict__ Wv, const float* __restrict__ Wa,
    const float* __restrict__ Wb, const float* __restrict__ Wg,
    __hip_bfloat16* __restrict__ dst)
{
    int e = blockIdx.x * 256 + threadIdx.x;  // < 4224*1024
    int r = e >> 10, c = e & 1023;
    float vv;
    if      (r <  512) vv = Wq[(size_t)r * 1024 + c];
    else if (r < 1024) vv = Wk[(size_t)(r -  512) * 1024 + c];
    else if (r < 2048) vv = Wv[(size_t)(r - 1024) * 1024 + c];
    else if (r < 3072) vv = Wa[(size_t)(r - 2048) * 1024 + c];
    else if (r < 3080) vv = Wb[(size_t)(r - 3072) * 1024 + c];
    else if (r < 4104) vv = Wg[(size_t)(r - 3080) * 1024 + c];
    else               vv = 0.0f;
    dst[e] = __float2bfloat16(vv);
}

// ---------------------------------------------------------------- GEMM 1 (fused epilogue, coalesced stores)
__global__ __launch_bounds__(256) void gemm1_kernel(
    const __hip_bfloat16* __restrict__ A, const __hip_bfloat16* __restrict__ Bw,
    float* __restrict__ qraw, float* __restrict__ kraw, float* __restrict__ vraw,
    float* __restrict__ abuf, float* __restrict__ betab, float* __restrict__ gbuf,
    const float* __restrict__ ba, const float* __restrict__ bb)
{
    constexpr int Kd = 1024;
    __shared__ __attribute__((aligned(16))) __hip_bfloat16 At[128 * 32];
    __shared__ __attribute__((aligned(16))) __hip_bfloat16 Bt[128 * 32];
    __shared__ __attribute__((aligned(16))) float Ct[4][16 * 68];  // per-wave transpose scratch
    const int tid = threadIdx.x;
    const int mBase = blockIdx.x * 128;
    const int nBase = blockIdx.y * 128;
    const int wave = tid >> 6, lane = tid & 63;
    const int wm = (wave >> 1) * 64, wn = (wave & 1) * 64;
    const int quad = lane >> 4, l16 = lane & 15;

    f32x4 acc[4][4];
    for (int i = 0; i < 4; i++)
        for (int j = 0; j < 4; j++)
            for (int r = 0; r < 4; r++) acc[i][j][r] = 0.0f;

    const int srow = tid >> 2;
    const int skk = (tid & 3) * 8;
    const __hip_bfloat16* Ag = A + (size_t)(mBase + srow) * Kd + skk;
    const __hip_bfloat16* Bg = Bw + (size_t)(nBase + srow) * Kd + skk;
    __hip_bfloat16* Al = &At[srow * 32 + skk];
    __hip_bfloat16* Bl = &Bt[srow * 32 + skk];

    for (int k0 = 0; k0 < Kd; k0 += 32) {
        GLDS(Ag + k0, Al);
        GLDS(Ag + k0 + (size_t)64 * Kd, Al + 64 * 32);
        GLDS(Bg + k0, Bl);
        GLDS(Bg + k0 + (size_t)64 * Kd, Bl + 64 * 32);
        __syncthreads();
        s16x8 af[4], bfr[4];
#pragma unroll
        for (int i = 0; i < 4; i++)
            af[i] = *(const s16x8*)&At[(wm + i * 16 + l16) * 32 + quad * 8];
#pragma unroll
        for (int j = 0; j < 4; j++)
            bfr[j] = *(const s16x8*)&Bt[(wn + j * 16 + l16) * 32 + quad * 8];
#pragma unroll
        for (int i = 0; i < 4; i++)
#pragma unroll
            for (int j = 0; j < 4; j++)
                acc[i][j] = __builtin_amdgcn_mfma_f32_16x16x32_bf16(af[i], bfr[j], acc[i][j], 0, 0, 0);
        __syncthreads();
    }

    const int ncol = nBase + wn + l16 * 4;
    float* basep; size_t rstr; bool dosig = false; bool skip = false;
    float4 bias = make_float4(0.f, 0.f, 0.f, 0.f);
    if (ncol < 512)       { basep = qraw + ncol;          rstr = 512;  }
    else if (ncol < 1024) { basep = kraw + (ncol - 512);  rstr = 512;  }
    else if (ncol < 2048) { basep = vraw + (ncol - 1024); rstr = 1024; }
    else if (ncol < 3072) { basep = abuf + (ncol - 2048); rstr = 1024; dosig = true;
                            bias = *(const float4*)(ba + (ncol - 2048)); }
    else if (ncol < 3080) { basep = betab + (ncol - 3072); rstr = 8;   dosig = true;
                            bias = *(const float4*)(bb + (ncol - 3072)); }
    else if (ncol < 4104) { basep = gbuf + (ncol - 3080); rstr = 1024; dosig = true; }
    else                  { basep = gbuf; rstr = 0; skip = true; }

#pragma unroll
    for (int i = 0; i < 4; i++) {
#pragma unroll
        for (int j = 0; j < 4; j++)
#pragma unroll
            for (int r = 0; r < 4; r++)
                Ct[wave][(quad * 4 + r) * 68 + j * 16 + l16] = acc[i][j][r];
        __syncthreads();
#pragma unroll
        for (int p = 0; p < 4; p++) {
            int rr = p * 4 + quad;
            float4 val = *(const float4*)&Ct[wave][rr * 68 + l16 * 4];
            if (dosig) {
                val.x = sigm(val.x + bias.x);
                val.y = sigm(val.y + bias.y);
                val.z = sigm(val.z + bias.z);
                val.w = sigm(val.w + bias.w);
            }
            int m = mBase + wm + i * 16 + rr;
            if (!skip) *(float4*)(basep + (size_t)m * rstr) = val;
        }
        __syncthreads();
    }
}

// ---------------------------------------------------------------- GEMM 2 (plain, coalesced stores)
__global__ __launch_bounds__(256) void gemm2_kernel(
    const __hip_bfloat16* __restrict__ A, const __hip_bfloat16* __restrict__ Bw,
    float* __restrict__ out)
{
    constexpr int Kd = 1024;
    __shared__ __attribute__((aligned(16))) __hip_bfloat16 At[128 * 32];
    __shared__ __attribute__((aligned(16))) __hip_bfloat16 Bt[128 * 32];
    __shared__ __attribute__((aligned(16))) float Ct[4][16 * 68];
    const int tid = threadIdx.x;
    const int mBase = blockIdx.x * 128;
    const int nBase = blockIdx.y * 128;
    const int wave = tid >> 6, lane = tid & 63;
    const int wm = (wave >> 1) * 64, wn = (wave & 1) * 64;
    const int quad = lane >> 4, l16 = lane & 15;

    f32x4 acc[4][4];
    for (int i = 0; i < 4; i++)
        for (int j = 0; j < 4; j++)
            for (int r = 0; r < 4; r++) acc[i][j][r] = 0.0f;

    const int srow = tid >> 2;
    const int skk = (tid & 3) * 8;
    const __hip_bfloat16* Ag = A + (size_t)(mBase + srow) * Kd + skk;
    const __hip_bfloat16* Bg = Bw + (size_t)(nBase + srow) * Kd + skk;
    __hip_bfloat16* Al = &At[srow * 32 + skk];
    __hip_bfloat16* Bl = &Bt[srow * 32 + skk];

    for (int k0 = 0; k0 < Kd; k0 += 32) {
        GLDS(Ag + k0, Al);
        GLDS(Ag + k0 + (size_t)64 * Kd, Al + 64 * 32);
        GLDS(Bg + k0, Bl);
        GLDS(Bg + k0 + (size_t)64 * Kd, Bl + 64 * 32);
        __syncthreads();
        s16x8 af[4], bfr[4];
#pragma unroll
        for (int i = 0; i < 4; i++)
            af[i] = *(const s16x8*)&At[(wm + i * 16 + l16) * 32 + quad * 8];
#pragma unroll
        for (int j = 0; j < 4; j++)
            bfr[j] = *(const s16x8*)&Bt[(wn + j * 16 + l16) * 32 + quad * 8];
#pragma unroll
        for (int i = 0; i < 4; i++)
#pragma unroll
            for (int j = 0; j < 4; j++)
                acc[i][j] = __builtin_amdgcn_mfma_f32_16x16x32_bf16(af[i], bfr[j], acc[i][j], 0, 0, 0);
        __syncthreads();
    }

    const int ncol = nBase + wn + l16 * 4;
    float* basep = out + ncol;
#pragma unroll
    for (int i = 0; i < 4; i++) {
#pragma unroll
        for (int j = 0; j < 4; j++)
#pragma unroll
            for (int r = 0; r < 4; r++)
                Ct[wave][(quad * 4 + r) * 68 + j * 16 + l16] = acc[i][j][r];
        __syncthreads();
#pragma unroll
        for (int p = 0; p < 4; p++) {
            int rr = p * 4 + quad;
            float4 val = *(const float4*)&Ct[wave][rr * 68 + l16 * 4];
            int m = mBase + wm + i * 16 + rr;
            *(float4*)(basep + (size_t)m * 1024) = val;
        }
        __syncthreads();
    }
}

// ---------------------------------------------------------------- depthwise causal conv (K=4) + SiLU
__global__ __launch_bounds__(256) void conv_silu_kernel(
    const float* __restrict__ src, const float* __restrict__ w4,
    const float* __restrict__ bias, float* __restrict__ dst,
    int C, int total, float scale)
{
    int e = blockIdx.x * 256 + threadIdx.x;
    if (e >= total) return;
    int c = e % C;
    int bt = e / C;
    int t = bt % TDIM;
    const float* wc = w4 + (size_t)c * 4;
    const float* s = src + (size_t)bt * C + c;
    float acc = bias[c];
    acc = fmaf(s[0], wc[3], acc);
    if (t >= 1) acc = fmaf(s[-C], wc[2], acc);
    if (t >= 2) acc = fmaf(s[-2 * C], wc[1], acc);
    if (t >= 3) acc = fmaf(s[-3 * C], wc[0], acc);
    dst[e] = acc * sigm(acc) * scale;
}

// ---------------------------------------------------------------- gated delta-rule scan v4
// 512 blocks x 64 threads. XCD swizzle: bh = bid&31 so the 16 blocks sharing a
// (b,h) k/q stream land on the same XCD residue (L2 locality). Prefetch depth
// NBUF-1 = 7 via rotating register buffers (fully unrolled -> constant idx).
#define NBUF 8

#define SCAN_LOADI(S_, TT) do {                                               \
    size_t ko = kqBase + (size_t)(TT) * 512;                                  \
    K0[S_] = *(const float4*)(kc + ko); K1[S_] = *(const float4*)(kc + ko + 4); \
    Q0[S_] = *(const float4*)(qc + ko); Q1[S_] = *(const float4*)(qc + ko + 4); \
    size_t vo = vaBase + (size_t)(TT) * 1024;                                 \
    Vb[S_] = vc[vo]; Ab[S_] = ab[vo]; Bb[S_] = betab[beBase + (size_t)(TT) * 8]; \
} while (0)

#define SCAN_STEPI(S_, TT) do {                                               \
    float4 k0 = K0[S_], k1 = K1[S_], q0 = Q0[S_], q1 = Q1[S_];                \
    float VV = Vb[S_], AA = Ab[S_], BB = Bb[S_];                              \
    float r0 = k0.x * S0, r1 = k0.y * S1;                                     \
    r0 = fmaf(k0.z, S2, r0); r1 = fmaf(k0.w, S3, r1);                         \
    r0 = fmaf(k1.x, S4, r0); r1 = fmaf(k1.y, S5, r1);                         \
    r0 = fmaf(k1.z, S6, r0); r1 = fmaf(k1.w, S7, r1);                         \
    float rr = reduce8(r0 + r1);                                              \
    float cc = BB * (rr - VV);                                                \
    float o0, o1;                                                             \
    S0 = fmaf(-cc, k0.x, AA * S0); o0 = q0.x * S0;                            \
    S1 = fmaf(-cc, k0.y, AA * S1); o1 = q0.y * S1;                            \
    S2 = fmaf(-cc, k0.z, AA * S2); o0 = fmaf(q0.z, S2, o0);                   \
    S3 = fmaf(-cc, k0.w, AA * S3); o1 = fmaf(q0.w, S3, o1);                   \
    S4 = fmaf(-cc, k1.x, AA * S4); o0 = fmaf(q1.x, S4, o0);                   \
    S5 = fmaf(-cc, k1.y, AA * S5); o1 = fmaf(q1.y, S5, o1);                   \
    S6 = fmaf(-cc, k1.z, AA * S6); o0 = fmaf(q1.z, S6, o0);                   \
    S7 = fmaf(-cc, k1.w, AA * S7); o1 = fmaf(q1.w, S7, o1);                   \
    float oo = reduce8(o0 + o1);                                              \
    if (ks == 0) ob[vaBase + (size_t)(TT) * 1024] = oo;                       \
} while (0)

#define WRAPT(X) ((X) < TDIM ? (X) : 0)

__global__ __launch_bounds__(64) void scan_kernel(
    const float* __restrict__ qc, const float* __restrict__ kc,
    const float* __restrict__ vc, const float* __restrict__ ab,
    const float* __restrict__ betab, float* __restrict__ ob)
{
    const int bid = blockIdx.x;
    const int bh = bid & 31, vg = bid >> 5;   // XCD-affinity: same bh -> same bid%8
    const int h = bh & 7, b = bh >> 3;
    const int lane = threadIdx.x;
    const int ks = lane & 7, vi = lane >> 3;
    const int v = vg * 8 + vi;
    float S0 = 0, S1 = 0, S2 = 0, S3 = 0, S4 = 0, S5 = 0, S6 = 0, S7 = 0;
    const size_t kqBase = ((size_t)b * TDIM * NH + h) * 64 + (size_t)ks * 8;  // +t*512
    const size_t vaBase = ((size_t)b * TDIM * NH + h) * 128 + v;               // +t*1024
    const size_t beBase = (size_t)b * TDIM * 8 + h;                            // +t*8

    float4 K0[NBUF], K1[NBUF], Q0[NBUF], Q1[NBUF];
    float Vb[NBUF], Ab[NBUF], Bb[NBUF];
#pragma unroll
    for (int i = 0; i < NBUF - 1; i++) SCAN_LOADI(i, i);
    for (int t = 0; t < TDIM; t += NBUF) {
#pragma unroll
        for (int i = 0; i < NBUF; i++) {
            SCAN_LOADI((i + NBUF - 1) % NBUF, WRAPT(t + i + NBUF - 1));
            SCAN_STEPI(i, t + i);
        }
    }
}

// ---------------------------------------------------------------- LayerNorm(DV=128) + gate -> bf16
__global__ __launch_bounds__(256) void ln_gate_kernel(
    const float* __restrict__ ob, const float* __restrict__ g,
    const float* __restrict__ lnw, const float* __restrict__ lnb,
    __hip_bfloat16* __restrict__ opr)
{
    int row = blockIdx.x * 4 + (threadIdx.x >> 6);
    int lane = threadIdx.x & 63;
    size_t base = (size_t)row * 128 + lane * 2;
    float2 xv = *(const float2*)(ob + base);
    float s = xv.x + xv.y;
#pragma unroll
    for (int m = 1; m <= 32; m <<= 1) s += __shfl_xor(s, m);
    float mean = s * (1.0f / 128.0f);
    float d0 = xv.x - mean, d1 = xv.y - mean;
    float vs = d0 * d0 + d1 * d1;
#pragma unroll
    for (int m = 1; m <= 32; m <<= 1) vs += __shfl_xor(vs, m);
    float rstd = rsqrtf(vs * (1.0f / 128.0f) + 1e-5f);
    float2 gv = *(const float2*)(g + base);
    float w0 = lnw[lane * 2], w1 = lnw[lane * 2 + 1];
    float b0 = lnb[lane * 2], b1 = lnb[lane * 2 + 1];
    opr[base] = __float2bfloat16((d0 * rstd * w0 + b0) * gv.x);
    opr[base + 1] = __float2bfloat16((d1 * rstd * w1 + b1) * gv.y);
}

// ---------------------------------------------------------------- launch
extern "C" void kernel_launch(void* const* d_in, const int* in_sizes, int n_in,
                              void* d_out, int out_size, void* d_ws, size_t ws_size,
                              hipStream_t stream)
{
    const float* x    = (const float*)d_in[0];
    const float* Wq   = (const float*)d_in[1];
    const float* Wk   = (const float*)d_in[2];
    const float* Wv   = (const float*)d_in[3];
    const float* Wa   = (const float*)d_in[4];
    const float* ba   = (const float*)d_in[5];
    const float* Wb   = (const float*)d_in[6];
    const float* bb   = (const float*)d_in[7];
    const float* Wg   = (const float*)d_in[8];
    const float* Wo   = (const float*)d_in[9];
    const float* qc_w = (const float*)d_in[10];
    const float* qc_b = (const float*)d_in[11];
    const float* kc_w = (const float*)d_in[12];
    const float* kc_b = (const float*)d_in[13];
    const float* vc_w = (const float*)d_in[14];
    const float* vc_b = (const float*)d_in[15];
    const float* ln_w = (const float*)d_in[16];
    const float* ln_b = (const float*)d_in[17];
    float* out = (float*)d_out;

    char* W = (char*)d_ws;
    __hip_bfloat16* xbf  = (__hip_bfloat16*)(W + 0);            // 16777216
    __hip_bfloat16* wcat = (__hip_bfloat16*)(W + 16777216);     // 8650752
    __hip_bfloat16* wobf = (__hip_bfloat16*)(W + 25427968);     // 2097152
    float* qraw  = (float*)(W + 27525120);                      // 16777216
    float* kraw  = (float*)(W + 44302336);                      // 16777216
    float* vraw  = (float*)(W + 61079552);                      // 33554432
    float* abuf  = (float*)(W + 94633984);                      // 33554432
    float* betab = (float*)(W + 128188416);                     // 262144
    float* gbuf  = (float*)(W + 128450560);                     // 33554432
    float* kcb   = (float*)(W + 162004992);                     // 16777216
    float* vcb   = (float*)(W + 178782208);                     // 33554432
    float* qcb   = (float*)xbf;                 // reuse: xbf dead after gemm1
    float* obuf  = (float*)qraw;                // reuse: qraw+kraw dead after convs
    __hip_bfloat16* opr = (__hip_bfloat16*)vraw;// reuse: vraw dead after conv-v

    pack_f32_bf16_kernel<<<8192, 256, 0, stream>>>(x, xbf, 2097152);
    pack_w_kernel<<<16896, 256, 0, stream>>>(Wq, Wk, Wv, Wa, Wb, Wg, wcat);
    pack_f32_bf16_kernel<<<1024, 256, 0, stream>>>(Wo, wobf, 262144);
    gemm1_kernel<<<dim3(64, 33), 256, 0, stream>>>(xbf, wcat, qraw, kraw, vraw,
                                                   abuf, betab, gbuf, ba, bb);
    conv_silu_kernel<<<16384, 256, 0, stream>>>(qraw, qc_w, qc_b, qcb, 512, 4194304, 1.0f);
    conv_silu_kernel<<<16384, 256, 0, stream>>>(kraw, kc_w, kc_b, kcb, 512, 4194304, 0.125f);
    conv_silu_kernel<<<32768, 256, 0, stream>>>(vraw, vc_w, vc_b, vcb, 1024, 8388608, 1.0f);
    scan_kernel<<<512, 64, 0, stream>>>(qcb, kcb, vcb, abuf, betab, obuf);
    ln_gate_kernel<<<16384, 256, 0, stream>>>(obuf, gbuf, ln_w, ln_b, opr);
    gemm2_kernel<<<dim3(64, 8), 256, 0, stream>>>(opr, wobf, out);
}

// Round 6
// 697.884 us; speedup vs baseline: 2.9511x; 1.1436x over previous
//
#include <hip/hip_runtime.h>
#include <hip/hip_bf16.h>
#include <cstdint>
#include <cstddef>

#define TDIM 2048
#define NH 8

using f32x4 = __attribute__((ext_vector_type(4))) float;
using s16x8 = __attribute__((ext_vector_type(8))) short;

__device__ __forceinline__ float sigm(float x) { return 1.0f / (1.0f + __expf(-x)); }

#define GLDS(gp, lp)                                                          \
    __builtin_amdgcn_global_load_lds(                                         \
        (const __attribute__((address_space(1))) void*)(gp),                  \
        (__attribute__((address_space(3))) void*)(lp), 16, 0, 0)
#define GLDS4(gp, lp)                                                         \
    __builtin_amdgcn_global_load_lds(                                         \
        (const __attribute__((address_space(1))) void*)(gp),                  \
        (__attribute__((address_space(3))) void*)(lp), 4, 0, 0)

// DPP-based 8-lane reduction (lanes grouped by low 3 bits).
template<int CTRL>
__device__ __forceinline__ float dpp_add(float x) {
    int p = __builtin_amdgcn_mov_dpp(__float_as_int(x), CTRL, 0xF, 0xF, true);
    return x + __int_as_float(p);
}
__device__ __forceinline__ float reduce8(float x) {
    x = dpp_add<0xB1>(x);   // quad_perm [1,0,3,2]
    x = dpp_add<0x4E>(x);   // quad_perm [2,3,0,1]
    x = dpp_add<0x141>(x);  // row_half_mirror (completes 8-lane sum)
    return x;
}

// ---------------------------------------------------------------- pack kernels
__global__ __launch_bounds__(256) void pack_f32_bf16_kernel(
    const float* __restrict__ src, __hip_bfloat16* __restrict__ dst, int n4)
{
    int i = blockIdx.x * 256 + threadIdx.x;
    if (i >= n4) return;
    float4 v = *(const float4*)(src + (size_t)i * 4);
    size_t o = (size_t)i * 4;
    dst[o + 0] = __float2bfloat16(v.x);
    dst[o + 1] = __float2bfloat16(v.y);
    dst[o + 2] = __float2bfloat16(v.z);
    dst[o + 3] = __float2bfloat16(v.w);
}

__global__ __launch_bounds__(256) void pack_w_kernel(
    const float* __restrict__ Wq, const float* __restrict__ Wk,
    const float* __restrict__ Wv, const float* __restrict__ Wa,
    const float* __restrict__ Wb, const float* __restrict__ Wg,
    __hip_bfloat16* __restrict__ dst)
{
    int e = blockIdx.x * 256 + threadIdx.x;  // < 4224*1024
    int r = e >> 10, c = e & 1023;
    float vv;
    if      (r <  512) vv = Wq[(size_t)r * 1024 + c];
    else if (r < 1024) vv = Wk[(size_t)(r -  512) * 1024 + c];
    else if (r < 2048) vv = Wv[(size_t)(r - 1024) * 1024 + c];
    else if (r < 3072) vv = Wa[(size_t)(r - 2048) * 1024 + c];
    else if (r < 3080) vv = Wb[(size_t)(r - 3072) * 1024 + c];
    else if (r < 4104) vv = Wg[(size_t)(r - 3080) * 1024 + c];
    else               vv = 0.0f;
    dst[e] = __float2bfloat16(vv);
}

// ---------------------------------------------------------------- GEMM 1 (fused epilogue, coalesced stores)
__global__ __launch_bounds__(256) void gemm1_kernel(
    const __hip_bfloat16* __restrict__ A, const __hip_bfloat16* __restrict__ Bw,
    float* __restrict__ qraw, float* __restrict__ kraw, float* __restrict__ vraw,
    float* __restrict__ abuf, float* __restrict__ betab, float* __restrict__ gbuf,
    const float* __restrict__ ba, const float* __restrict__ bb)
{
    constexpr int Kd = 1024;
    __shared__ __attribute__((aligned(16))) __hip_bfloat16 At[128 * 32];
    __shared__ __attribute__((aligned(16))) __hip_bfloat16 Bt[128 * 32];
    __shared__ __attribute__((aligned(16))) float Ct[4][16 * 68];
    const int tid = threadIdx.x;
    const int mBase = blockIdx.x * 128;
    const int nBase = blockIdx.y * 128;
    const int wave = tid >> 6, lane = tid & 63;
    const int wm = (wave >> 1) * 64, wn = (wave & 1) * 64;
    const int quad = lane >> 4, l16 = lane & 15;

    f32x4 acc[4][4];
    for (int i = 0; i < 4; i++)
        for (int j = 0; j < 4; j++)
            for (int r = 0; r < 4; r++) acc[i][j][r] = 0.0f;

    const int srow = tid >> 2;
    const int skk = (tid & 3) * 8;
    const __hip_bfloat16* Ag = A + (size_t)(mBase + srow) * Kd + skk;
    const __hip_bfloat16* Bg = Bw + (size_t)(nBase + srow) * Kd + skk;
    __hip_bfloat16* Al = &At[srow * 32 + skk];
    __hip_bfloat16* Bl = &Bt[srow * 32 + skk];

    for (int k0 = 0; k0 < Kd; k0 += 32) {
        GLDS(Ag + k0, Al);
        GLDS(Ag + k0 + (size_t)64 * Kd, Al + 64 * 32);
        GLDS(Bg + k0, Bl);
        GLDS(Bg + k0 + (size_t)64 * Kd, Bl + 64 * 32);
        __syncthreads();
        s16x8 af[4], bfr[4];
#pragma unroll
        for (int i = 0; i < 4; i++)
            af[i] = *(const s16x8*)&At[(wm + i * 16 + l16) * 32 + quad * 8];
#pragma unroll
        for (int j = 0; j < 4; j++)
            bfr[j] = *(const s16x8*)&Bt[(wn + j * 16 + l16) * 32 + quad * 8];
#pragma unroll
        for (int i = 0; i < 4; i++)
#pragma unroll
            for (int j = 0; j < 4; j++)
                acc[i][j] = __builtin_amdgcn_mfma_f32_16x16x32_bf16(af[i], bfr[j], acc[i][j], 0, 0, 0);
        __syncthreads();
    }

    const int ncol = nBase + wn + l16 * 4;
    float* basep; size_t rstr; bool dosig = false; bool skip = false;
    float4 bias = make_float4(0.f, 0.f, 0.f, 0.f);
    if (ncol < 512)       { basep = qraw + ncol;          rstr = 512;  }
    else if (ncol < 1024) { basep = kraw + (ncol - 512);  rstr = 512;  }
    else if (ncol < 2048) { basep = vraw + (ncol - 1024); rstr = 1024; }
    else if (ncol < 3072) { basep = abuf + (ncol - 2048); rstr = 1024; dosig = true;
                            bias = *(const float4*)(ba + (ncol - 2048)); }
    else if (ncol < 3080) { basep = betab + (ncol - 3072); rstr = 8;   dosig = true;
                            bias = *(const float4*)(bb + (ncol - 3072)); }
    else if (ncol < 4104) { basep = gbuf + (ncol - 3080); rstr = 1024; dosig = true; }
    else                  { basep = gbuf; rstr = 0; skip = true; }

#pragma unroll
    for (int i = 0; i < 4; i++) {
#pragma unroll
        for (int j = 0; j < 4; j++)
#pragma unroll
            for (int r = 0; r < 4; r++)
                Ct[wave][(quad * 4 + r) * 68 + j * 16 + l16] = acc[i][j][r];
        __syncthreads();
#pragma unroll
        for (int p = 0; p < 4; p++) {
            int rr = p * 4 + quad;
            float4 val = *(const float4*)&Ct[wave][rr * 68 + l16 * 4];
            if (dosig) {
                val.x = sigm(val.x + bias.x);
                val.y = sigm(val.y + bias.y);
                val.z = sigm(val.z + bias.z);
                val.w = sigm(val.w + bias.w);
            }
            int m = mBase + wm + i * 16 + rr;
            if (!skip) *(float4*)(basep + (size_t)m * rstr) = val;
        }
        __syncthreads();
    }
}

// ---------------------------------------------------------------- GEMM 2 (plain, coalesced stores)
__global__ __launch_bounds__(256) void gemm2_kernel(
    const __hip_bfloat16* __restrict__ A, const __hip_bfloat16* __restrict__ Bw,
    float* __restrict__ out)
{
    constexpr int Kd = 1024;
    __shared__ __attribute__((aligned(16))) __hip_bfloat16 At[128 * 32];
    __shared__ __attribute__((aligned(16))) __hip_bfloat16 Bt[128 * 32];
    __shared__ __attribute__((aligned(16))) float Ct[4][16 * 68];
    const int tid = threadIdx.x;
    const int mBase = blockIdx.x * 128;
    const int nBase = blockIdx.y * 128;
    const int wave = tid >> 6, lane = tid & 63;
    const int wm = (wave >> 1) * 64, wn = (wave & 1) * 64;
    const int quad = lane >> 4, l16 = lane & 15;

    f32x4 acc[4][4];
    for (int i = 0; i < 4; i++)
        for (int j = 0; j < 4; j++)
            for (int r = 0; r < 4; r++) acc[i][j][r] = 0.0f;

    const int srow = tid >> 2;
    const int skk = (tid & 3) * 8;
    const __hip_bfloat16* Ag = A + (size_t)(mBase + srow) * Kd + skk;
    const __hip_bfloat16* Bg = Bw + (size_t)(nBase + srow) * Kd + skk;
    __hip_bfloat16* Al = &At[srow * 32 + skk];
    __hip_bfloat16* Bl = &Bt[srow * 32 + skk];

    for (int k0 = 0; k0 < Kd; k0 += 32) {
        GLDS(Ag + k0, Al);
        GLDS(Ag + k0 + (size_t)64 * Kd, Al + 64 * 32);
        GLDS(Bg + k0, Bl);
        GLDS(Bg + k0 + (size_t)64 * Kd, Bl + 64 * 32);
        __syncthreads();
        s16x8 af[4], bfr[4];
#pragma unroll
        for (int i = 0; i < 4; i++)
            af[i] = *(const s16x8*)&At[(wm + i * 16 + l16) * 32 + quad * 8];
#pragma unroll
        for (int j = 0; j < 4; j++)
            bfr[j] = *(const s16x8*)&Bt[(wn + j * 16 + l16) * 32 + quad * 8];
#pragma unroll
        for (int i = 0; i < 4; i++)
#pragma unroll
            for (int j = 0; j < 4; j++)
                acc[i][j] = __builtin_amdgcn_mfma_f32_16x16x32_bf16(af[i], bfr[j], acc[i][j], 0, 0, 0);
        __syncthreads();
    }

    const int ncol = nBase + wn + l16 * 4;
    float* basep = out + ncol;
#pragma unroll
    for (int i = 0; i < 4; i++) {
#pragma unroll
        for (int j = 0; j < 4; j++)
#pragma unroll
            for (int r = 0; r < 4; r++)
                Ct[wave][(quad * 4 + r) * 68 + j * 16 + l16] = acc[i][j][r];
        __syncthreads();
#pragma unroll
        for (int p = 0; p < 4; p++) {
            int rr = p * 4 + quad;
            float4 val = *(const float4*)&Ct[wave][rr * 68 + l16 * 4];
            int m = mBase + wm + i * 16 + rr;
            *(float4*)(basep + (size_t)m * 1024) = val;
        }
        __syncthreads();
    }
}

// ---------------------------------------------------------------- depthwise causal conv (K=4) + SiLU
__global__ __launch_bounds__(256) void conv_silu_kernel(
    const float* __restrict__ src, const float* __restrict__ w4,
    const float* __restrict__ bias, float* __restrict__ dst,
    int C, int total, float scale)
{
    int e = blockIdx.x * 256 + threadIdx.x;
    if (e >= total) return;
    int c = e % C;
    int bt = e / C;
    int t = bt % TDIM;
    const float* wc = w4 + (size_t)c * 4;
    const float* s = src + (size_t)bt * C + c;
    float acc = bias[c];
    acc = fmaf(s[0], wc[3], acc);
    if (t >= 1) acc = fmaf(s[-C], wc[2], acc);
    if (t >= 2) acc = fmaf(s[-2 * C], wc[1], acc);
    if (t >= 3) acc = fmaf(s[-3 * C], wc[0], acc);
    dst[e] = acc * sigm(acc) * scale;
}

// ---------------------------------------------------------------- gated delta-rule scan v5 (LDS-staged)
// 512 blocks x 64 threads, XCD swizzle (bh = bid&31). Chunked: 32 steps per
// chunk, double-buffered LDS filled by async global_load_lds issued one full
// chunk ahead (vmcnt drain folded into the per-chunk __syncthreads -> load
// latency amortized /32 steps, compiler cannot sink it onto the serial chain).
// Per step: 4 ds_read_b128 (2-way conflict = free) + 3 ds_read_b32
// (broadcast) feeding the same DPP-reduce recurrence. Output staged in LDS,
// one coalesced float4 store per lane per chunk.
#define CH 32
#define NCHUNK (TDIM / CH)

#define SCAN_STAGE(BUF, T0) do {                                              \
    _Pragma("unroll") for (int j = 0; j < 8; j++) {                           \
        int flat = j * 64 + lane;                                             \
        int tt = flat >> 4, c4 = (flat & 15) * 4;                             \
        GLDS(kc + kqB + (size_t)((T0) + tt) * 512 + c4, &kL[BUF][j * 256]);   \
        GLDS(qc + kqB + (size_t)((T0) + tt) * 512 + c4, &qL[BUF][j * 256]);   \
    }                                                                         \
    {                                                                         \
        int tt = lane >> 1, c4 = (lane & 1) * 4;                              \
        GLDS(vc + vaB + (size_t)((T0) + tt) * 1024 + c4, &vL[BUF][0]);        \
        GLDS(ab + vaB + (size_t)((T0) + tt) * 1024 + c4, &aL[BUF][0]);        \
    }                                                                         \
    if (lane < 32)                                                            \
        GLDS4(betab + beB + (size_t)((T0) + lane) * 8, &bL[BUF][0]);          \
} while (0)

#define SCAN_LSTEP(BUF, TT) do {                                              \
    const float4 k0 = *(const float4*)&kL[BUF][(TT) * 64 + ks * 8];           \
    const float4 k1 = *(const float4*)&kL[BUF][(TT) * 64 + ks * 8 + 4];       \
    const float4 q0 = *(const float4*)&qL[BUF][(TT) * 64 + ks * 8];           \
    const float4 q1 = *(const float4*)&qL[BUF][(TT) * 64 + ks * 8 + 4];       \
    const float VV = vL[BUF][(TT) * 8 + vi];                                  \
    const float AA = aL[BUF][(TT) * 8 + vi];                                  \
    const float BB = bL[BUF][TT];                                             \
    float r0 = k0.x * S0, r1 = k0.y * S1;                                     \
    r0 = fmaf(k0.z, S2, r0); r1 = fmaf(k0.w, S3, r1);                         \
    r0 = fmaf(k1.x, S4, r0); r1 = fmaf(k1.y, S5, r1);                         \
    r0 = fmaf(k1.z, S6, r0); r1 = fmaf(k1.w, S7, r1);                         \
    float rr = reduce8(r0 + r1);                                              \
    float cc = BB * (rr - VV);                                                \
    float o0, o1;                                                             \
    S0 = fmaf(-cc, k0.x, AA * S0); o0 = q0.x * S0;                            \
    S1 = fmaf(-cc, k0.y, AA * S1); o1 = q0.y * S1;                            \
    S2 = fmaf(-cc, k0.z, AA * S2); o0 = fmaf(q0.z, S2, o0);                   \
    S3 = fmaf(-cc, k0.w, AA * S3); o1 = fmaf(q0.w, S3, o1);                   \
    S4 = fmaf(-cc, k1.x, AA * S4); o0 = fmaf(q1.x, S4, o0);                   \
    S5 = fmaf(-cc, k1.y, AA * S5); o1 = fmaf(q1.y, S5, o1);                   \
    S6 = fmaf(-cc, k1.z, AA * S6); o0 = fmaf(q1.z, S6, o0);                   \
    S7 = fmaf(-cc, k1.w, AA * S7); o1 = fmaf(q1.w, S7, o1);                   \
    float oo = reduce8(o0 + o1);                                              \
    if (ks == 0) oL[BUF][(TT) * 8 + vi] = oo;                                 \
} while (0)

__global__ __launch_bounds__(64) void scan_kernel(
    const float* __restrict__ qc, const float* __restrict__ kc,
    const float* __restrict__ vc, const float* __restrict__ ab,
    const float* __restrict__ betab, float* __restrict__ ob)
{
    __shared__ __attribute__((aligned(16))) float kL[2][CH * 64];
    __shared__ __attribute__((aligned(16))) float qL[2][CH * 64];
    __shared__ __attribute__((aligned(16))) float vL[2][CH * 8];
    __shared__ __attribute__((aligned(16))) float aL[2][CH * 8];
    __shared__ __attribute__((aligned(16))) float bL[2][CH];
    __shared__ __attribute__((aligned(16))) float oL[2][CH * 8];

    const int bid = blockIdx.x;
    const int bh = bid & 31, vg = bid >> 5;   // XCD-affinity swizzle
    const int h = bh & 7, b = bh >> 3;
    const int lane = threadIdx.x;
    const int ks = lane & 7, vi = lane >> 3;

    const size_t kqB = (size_t)b * TDIM * 512 + (size_t)h * 64;
    const size_t vaB = (size_t)b * TDIM * 1024 + (size_t)h * 128 + (size_t)vg * 8;
    const size_t beB = (size_t)b * TDIM * 8 + h;

    float S0 = 0, S1 = 0, S2 = 0, S3 = 0, S4 = 0, S5 = 0, S6 = 0, S7 = 0;

    SCAN_STAGE(0, 0);
    __syncthreads();
    for (int chk = 0; chk < NCHUNK; chk++) {
        const int buf = chk & 1;
        const int nb = buf ^ 1;
        const int tn = (chk + 1 < NCHUNK) ? (chk + 1) * CH : 0;
        SCAN_STAGE(nb, tn);
#pragma unroll 8
        for (int t = 0; t < CH; t++) SCAN_LSTEP(buf, t);
        __syncthreads();  // staged loads done + oL visible
        {
            int tt = lane >> 1, c4 = (lane & 1) * 4;
            *(float4*)(ob + vaB + (size_t)(chk * CH + tt) * 1024 + c4) =
                *(const float4*)&oL[buf][lane * 4];
        }
    }
}

// ---------------------------------------------------------------- LayerNorm(DV=128) + gate -> bf16
__global__ __launch_bounds__(256) void ln_gate_kernel(
    const float* __restrict__ ob, const float* __restrict__ g,
    const float* __restrict__ lnw, const float* __restrict__ lnb,
    __hip_bfloat16* __restrict__ opr)
{
    int row = blockIdx.x * 4 + (threadIdx.x >> 6);
    int lane = threadIdx.x & 63;
    size_t base = (size_t)row * 128 + lane * 2;
    float2 xv = *(const float2*)(ob + base);
    float s = xv.x + xv.y;
#pragma unroll
    for (int m = 1; m <= 32; m <<= 1) s += __shfl_xor(s, m);
    float mean = s * (1.0f / 128.0f);
    float d0 = xv.x - mean, d1 = xv.y - mean;
    float vs = d0 * d0 + d1 * d1;
#pragma unroll
    for (int m = 1; m <= 32; m <<= 1) vs += __shfl_xor(vs, m);
    float rstd = rsqrtf(vs * (1.0f / 128.0f) + 1e-5f);
    float2 gv = *(const float2*)(g + base);
    float w0 = lnw[lane * 2], w1 = lnw[lane * 2 + 1];
    float b0 = lnb[lane * 2], b1 = lnb[lane * 2 + 1];
    opr[base] = __float2bfloat16((d0 * rstd * w0 + b0) * gv.x);
    opr[base + 1] = __float2bfloat16((d1 * rstd * w1 + b1) * gv.y);
}

// ---------------------------------------------------------------- launch
extern "C" void kernel_launch(void* const* d_in, const int* in_sizes, int n_in,
                              void* d_out, int out_size, void* d_ws, size_t ws_size,
                              hipStream_t stream)
{
    const float* x    = (const float*)d_in[0];
    const float* Wq   = (const float*)d_in[1];
    const float* Wk   = (const float*)d_in[2];
    const float* Wv   = (const float*)d_in[3];
    const float* Wa   = (const float*)d_in[4];
    const float* ba   = (const float*)d_in[5];
    const float* Wb   = (const float*)d_in[6];
    const float* bb   = (const float*)d_in[7];
    const float* Wg   = (const float*)d_in[8];
    const float* Wo   = (const float*)d_in[9];
    const float* qc_w = (const float*)d_in[10];
    const float* qc_b = (const float*)d_in[11];
    const float* kc_w = (const float*)d_in[12];
    const float* kc_b = (const float*)d_in[13];
    const float* vc_w = (const float*)d_in[14];
    const float* vc_b = (const float*)d_in[15];
    const float* ln_w = (const float*)d_in[16];
    const float* ln_b = (const float*)d_in[17];
    float* out = (float*)d_out;

    char* W = (char*)d_ws;
    __hip_bfloat16* xbf  = (__hip_bfloat16*)(W + 0);            // 16777216
    __hip_bfloat16* wcat = (__hip_bfloat16*)(W + 16777216);     // 8650752
    __hip_bfloat16* wobf = (__hip_bfloat16*)(W + 25427968);     // 2097152
    float* qraw  = (float*)(W + 27525120);                      // 16777216
    float* kraw  = (float*)(W + 44302336);                      // 16777216
    float* vraw  = (float*)(W + 61079552);                      // 33554432
    float* abuf  = (float*)(W + 94633984);                      // 33554432
    float* betab = (float*)(W + 128188416);                     // 262144
    float* gbuf  = (float*)(W + 128450560);                     // 33554432
    float* kcb   = (float*)(W + 162004992);                     // 16777216
    float* vcb   = (float*)(W + 178782208);                     // 33554432
    float* qcb   = (float*)xbf;                 // reuse: xbf dead after gemm1
    float* obuf  = (float*)qraw;                // reuse: qraw+kraw dead after convs
    __hip_bfloat16* opr = (__hip_bfloat16*)vraw;// reuse: vraw dead after conv-v

    pack_f32_bf16_kernel<<<8192, 256, 0, stream>>>(x, xbf, 2097152);
    pack_w_kernel<<<16896, 256, 0, stream>>>(Wq, Wk, Wv, Wa, Wb, Wg, wcat);
    pack_f32_bf16_kernel<<<1024, 256, 0, stream>>>(Wo, wobf, 262144);
    gemm1_kernel<<<dim3(64, 33), 256, 0, stream>>>(xbf, wcat, qraw, kraw, vraw,
                                                   abuf, betab, gbuf, ba, bb);
    conv_silu_kernel<<<16384, 256, 0, stream>>>(qraw, qc_w, qc_b, qcb, 512, 4194304, 1.0f);
    conv_silu_kernel<<<16384, 256, 0, stream>>>(kraw, kc_w, kc_b, kcb, 512, 4194304, 0.125f);
    conv_silu_kernel<<<32768, 256, 0, stream>>>(vraw, vc_w, vc_b, vcb, 1024, 8388608, 1.0f);
    scan_kernel<<<512, 64, 0, stream>>>(qcb, kcb, vcb, abuf, betab, obuf);
    ln_gate_kernel<<<16384, 256, 0, stream>>>(obuf, gbuf, ln_w, ln_b, opr);
    gemm2_kernel<<<dim3(64, 8), 256, 0, stream>>>(opr, wobf, out);
}

// Round 9
// 673.529 us; speedup vs baseline: 3.0578x; 1.0362x over previous
//
#include <hip/hip_runtime.h>
#include <hip/hip_bf16.h>
#include <cstdint>
#include <cstddef>

#define TDIM 2048
#define NH 8

using f32x4 = __attribute__((ext_vector_type(4))) float;
using s16x8 = __attribute__((ext_vector_type(8))) short;

__device__ __forceinline__ float sigm(float x) { return 1.0f / (1.0f + __expf(-x)); }

#define GLDS(gp, lp)                                                          \
    __builtin_amdgcn_global_load_lds(                                         \
        (const __attribute__((address_space(1))) void*)(gp),                  \
        (__attribute__((address_space(3))) void*)(lp), 16, 0, 0)
#define GLDS4(gp, lp)                                                         \
    __builtin_amdgcn_global_load_lds(                                         \
        (const __attribute__((address_space(1))) void*)(gp),                  \
        (__attribute__((address_space(3))) void*)(lp), 4, 0, 0)

// DPP cross-lane adds (VALU pipe, no LDS).
template<int CTRL>
__device__ __forceinline__ float dpp_add(float x) {
    int p = __builtin_amdgcn_mov_dpp(__float_as_int(x), CTRL, 0xF, 0xF, true);
    return x + __int_as_float(p);
}
// sum over 16 lanes (low 4 bits of lane id): xor1, xor2, xor7, xor15
__device__ __forceinline__ float reduce16(float x) {
    x = dpp_add<0xB1>(x);   // quad_perm [1,0,3,2]
    x = dpp_add<0x4E>(x);   // quad_perm [2,3,0,1]
    x = dpp_add<0x141>(x);  // row_half_mirror (xor7)
    x = dpp_add<0x140>(x);  // row_mirror (xor15)
    return x;
}

// ---------------------------------------------------------------- pack kernels
__global__ __launch_bounds__(256) void pack_f32_bf16_kernel(
    const float* __restrict__ src, __hip_bfloat16* __restrict__ dst, int n4)
{
    int i = blockIdx.x * 256 + threadIdx.x;
    if (i >= n4) return;
    float4 v = *(const float4*)(src + (size_t)i * 4);
    size_t o = (size_t)i * 4;
    dst[o + 0] = __float2bfloat16(v.x);
    dst[o + 1] = __float2bfloat16(v.y);
    dst[o + 2] = __float2bfloat16(v.z);
    dst[o + 3] = __float2bfloat16(v.w);
}

__global__ __launch_bounds__(256) void pack_w_kernel(
    const float* __restrict__ Wq, const float* __restrict__ Wk,
    const float* __restrict__ Wv, const float* __restrict__ Wa,
    const float* __restrict__ Wb, const float* __restrict__ Wg,
    __hip_bfloat16* __restrict__ dst)
{
    int e = blockIdx.x * 256 + threadIdx.x;  // < 4224*1024
    int r = e >> 10, c = e & 1023;
    float vv;
    if      (r <  512) vv = Wq[(size_t)r * 1024 + c];
    else if (r < 1024) vv = Wk[(size_t)(r -  512) * 1024 + c];
    else if (r < 2048) vv = Wv[(size_t)(r - 1024) * 1024 + c];
    else if (r < 3072) vv = Wa[(size_t)(r - 2048) * 1024 + c];
    else if (r < 3080) vv = Wb[(size_t)(r - 3072) * 1024 + c];
    else if (r < 4104) vv = Wg[(size_t)(r - 3080) * 1024 + c];
    else               vv = 0.0f;
    dst[e] = __float2bfloat16(vv);
}

// ---------------------------------------------------------------- GEMM 1 (fused epilogue, coalesced stores)
__global__ __launch_bounds__(256) void gemm1_kernel(
    const __hip_bfloat16* __restrict__ A, const __hip_bfloat16* __restrict__ Bw,
    float* __restrict__ qraw, float* __restrict__ kraw, float* __restrict__ vraw,
    float* __restrict__ abuf, float* __restrict__ betab, float* __restrict__ gbuf,
    const float* __restrict__ ba, const float* __restrict__ bb)
{
    constexpr int Kd = 1024;
    __shared__ __attribute__((aligned(16))) __hip_bfloat16 At[128 * 32];
    __shared__ __attribute__((aligned(16))) __hip_bfloat16 Bt[128 * 32];
    __shared__ __attribute__((aligned(16))) float Ct[4][16 * 68];
    const int tid = threadIdx.x;
    const int mBase = blockIdx.x * 128;
    const int nBase = blockIdx.y * 128;
    const int wave = tid >> 6, lane = tid & 63;
    const int wm = (wave >> 1) * 64, wn = (wave & 1) * 64;
    const int quad = lane >> 4, l16 = lane & 15;

    f32x4 acc[4][4];
    for (int i = 0; i < 4; i++)
        for (int j = 0; j < 4; j++)
            for (int r = 0; r < 4; r++) acc[i][j][r] = 0.0f;

    const int srow = tid >> 2;
    const int skk = (tid & 3) * 8;
    const __hip_bfloat16* Ag = A + (size_t)(mBase + srow) * Kd + skk;
    const __hip_bfloat16* Bg = Bw + (size_t)(nBase + srow) * Kd + skk;
    __hip_bfloat16* Al = &At[srow * 32 + skk];
    __hip_bfloat16* Bl = &Bt[srow * 32 + skk];

    for (int k0 = 0; k0 < Kd; k0 += 32) {
        GLDS(Ag + k0, Al);
        GLDS(Ag + k0 + (size_t)64 * Kd, Al + 64 * 32);
        GLDS(Bg + k0, Bl);
        GLDS(Bg + k0 + (size_t)64 * Kd, Bl + 64 * 32);
        __syncthreads();
        s16x8 af[4], bfr[4];
#pragma unroll
        for (int i = 0; i < 4; i++)
            af[i] = *(const s16x8*)&At[(wm + i * 16 + l16) * 32 + quad * 8];
#pragma unroll
        for (int j = 0; j < 4; j++)
            bfr[j] = *(const s16x8*)&Bt[(wn + j * 16 + l16) * 32 + quad * 8];
#pragma unroll
        for (int i = 0; i < 4; i++)
#pragma unroll
            for (int j = 0; j < 4; j++)
                acc[i][j] = __builtin_amdgcn_mfma_f32_16x16x32_bf16(af[i], bfr[j], acc[i][j], 0, 0, 0);
        __syncthreads();
    }

    const int ncol = nBase + wn + l16 * 4;
    float* basep; size_t rstr; bool dosig = false; bool skip = false;
    float4 bias = make_float4(0.f, 0.f, 0.f, 0.f);
    if (ncol < 512)       { basep = qraw + ncol;          rstr = 512;  }
    else if (ncol < 1024) { basep = kraw + (ncol - 512);  rstr = 512;  }
    else if (ncol < 2048) { basep = vraw + (ncol - 1024); rstr = 1024; }
    else if (ncol < 3072) { basep = abuf + (ncol - 2048); rstr = 1024; dosig = true;
                            bias = *(const float4*)(ba + (ncol - 2048)); }
    else if (ncol < 3080) { basep = betab + (ncol - 3072); rstr = 8;   dosig = true;
                            bias = *(const float4*)(bb + (ncol - 3072)); }
    else if (ncol < 4104) { basep = gbuf + (ncol - 3080); rstr = 1024; dosig = true; }
    else                  { basep = gbuf; rstr = 0; skip = true; }

#pragma unroll
    for (int i = 0; i < 4; i++) {
#pragma unroll
        for (int j = 0; j < 4; j++)
#pragma unroll
            for (int r = 0; r < 4; r++)
                Ct[wave][(quad * 4 + r) * 68 + j * 16 + l16] = acc[i][j][r];
        __syncthreads();
#pragma unroll
        for (int p = 0; p < 4; p++) {
            int rr = p * 4 + quad;
            float4 val = *(const float4*)&Ct[wave][rr * 68 + l16 * 4];
            if (dosig) {
                val.x = sigm(val.x + bias.x);
                val.y = sigm(val.y + bias.y);
                val.z = sigm(val.z + bias.z);
                val.w = sigm(val.w + bias.w);
            }
            int m = mBase + wm + i * 16 + rr;
            if (!skip) *(float4*)(basep + (size_t)m * rstr) = val;
        }
        __syncthreads();
    }
}

// ---------------------------------------------------------------- GEMM 2 (plain, coalesced stores)
__global__ __launch_bounds__(256) void gemm2_kernel(
    const __hip_bfloat16* __restrict__ A, const __hip_bfloat16* __restrict__ Bw,
    float* __restrict__ out)
{
    constexpr int Kd = 1024;
    __shared__ __attribute__((aligned(16))) __hip_bfloat16 At[128 * 32];
    __shared__ __attribute__((aligned(16))) __hip_bfloat16 Bt[128 * 32];
    __shared__ __attribute__((aligned(16))) float Ct[4][16 * 68];
    const int tid = threadIdx.x;
    const int mBase = blockIdx.x * 128;
    const int nBase = blockIdx.y * 128;
    const int wave = tid >> 6, lane = tid & 63;
    const int wm = (wave >> 1) * 64, wn = (wave & 1) * 64;
    const int quad = lane >> 4, l16 = lane & 15;

    f32x4 acc[4][4];
    for (int i = 0; i < 4; i++)
        for (int j = 0; j < 4; j++)
            for (int r = 0; r < 4; r++) acc[i][j][r] = 0.0f;

    const int srow = tid >> 2;
    const int skk = (tid & 3) * 8;
    const __hip_bfloat16* Ag = A + (size_t)(mBase + srow) * Kd + skk;
    const __hip_bfloat16* Bg = Bw + (size_t)(nBase + srow) * Kd + skk;
    __hip_bfloat16* Al = &At[srow * 32 + skk];
    __hip_bfloat16* Bl = &Bt[srow * 32 + skk];

    for (int k0 = 0; k0 < Kd; k0 += 32) {
        GLDS(Ag + k0, Al);
        GLDS(Ag + k0 + (size_t)64 * Kd, Al + 64 * 32);
        GLDS(Bg + k0, Bl);
        GLDS(Bg + k0 + (size_t)64 * Kd, Bl + 64 * 32);
        __syncthreads();
        s16x8 af[4], bfr[4];
#pragma unroll
        for (int i = 0; i < 4; i++)
            af[i] = *(const s16x8*)&At[(wm + i * 16 + l16) * 32 + quad * 8];
#pragma unroll
        for (int j = 0; j < 4; j++)
            bfr[j] = *(const s16x8*)&Bt[(wn + j * 16 + l16) * 32 + quad * 8];
#pragma unroll
        for (int i = 0; i < 4; i++)
#pragma unroll
            for (int j = 0; j < 4; j++)
                acc[i][j] = __builtin_amdgcn_mfma_f32_16x16x32_bf16(af[i], bfr[j], acc[i][j], 0, 0, 0);
        __syncthreads();
    }

    const int ncol = nBase + wn + l16 * 4;
    float* basep = out + ncol;
#pragma unroll
    for (int i = 0; i < 4; i++) {
#pragma unroll
        for (int j = 0; j < 4; j++)
#pragma unroll
            for (int r = 0; r < 4; r++)
                Ct[wave][(quad * 4 + r) * 68 + j * 16 + l16] = acc[i][j][r];
        __syncthreads();
#pragma unroll
        for (int p = 0; p < 4; p++) {
            int rr = p * 4 + quad;
            float4 val = *(const float4*)&Ct[wave][rr * 68 + l16 * 4];
            int m = mBase + wm + i * 16 + rr;
            *(float4*)(basep + (size_t)m * 1024) = val;
        }
        __syncthreads();
    }
}

// ---------------------------------------------------------------- fused depthwise causal conv (K=4) + SiLU
__global__ __launch_bounds__(256) void conv_silu_fused_kernel(
    const float* __restrict__ qraw, const float* __restrict__ kraw,
    const float* __restrict__ vraw,
    const float* __restrict__ qw, const float* __restrict__ qb,
    const float* __restrict__ kw, const float* __restrict__ kb,
    const float* __restrict__ vw, const float* __restrict__ vb,
    float* __restrict__ qcb, float* __restrict__ kcb, float* __restrict__ vcb)
{
    int e = blockIdx.x * 256 + threadIdx.x;   // [0, 8192*2048)
    int c = e & 2047;
    int bt = e >> 11;
    int t = bt & (TDIM - 1);
    const float* src; float* dst; const float* w4; const float* bi;
    int C, cc; float scale = 1.0f;
    if (c < 512)       { src = qraw; dst = qcb; w4 = qw; bi = qb; C = 512;  cc = c; }
    else if (c < 1024) { src = kraw; dst = kcb; w4 = kw; bi = kb; C = 512;  cc = c - 512; scale = 0.125f; }
    else               { src = vraw; dst = vcb; w4 = vw; bi = vb; C = 1024; cc = c - 1024; }
    const float* wc = w4 + (size_t)cc * 4;
    const float* s = src + (size_t)bt * C + cc;
    float acc = bi[cc];
    acc = fmaf(s[0], wc[3], acc);
    if (t >= 1) acc = fmaf(s[-C], wc[2], acc);
    if (t >= 2) acc = fmaf(s[-2 * C], wc[1], acc);
    if (t >= 3) acc = fmaf(s[-3 * C], wc[0], acc);
    dst[(size_t)bt * C + cc] = acc * sigm(acc) * scale;
}

// ---------------------------------------------------------------- gated delta-rule scan v6b
// 1024 blocks x 64 threads (1 wave each) -> 1 wave on every SIMD.
// lane: ks = lane&15 (16 k-slices of 4), vi = lane>>4 (4 v-cols per wave).
// State: 4 floats/lane. Reductions: 4-stage DPP over 16 lanes.
// Staging uses ONLY full-wave GLDS16 / GLDS4 plus the v5-proven masked GLDS4
// (masked 16B global_load_lds removed — suspected container-killer in v6).
#define CH 32
#define NCHUNK (TDIM / CH)

#define SCAN_STAGE(BUF, T0) do {                                              \
    _Pragma("unroll") for (int j = 0; j < 8; j++) {                           \
        int flat = j * 64 + lane;                                             \
        int tt = flat >> 4, c4 = (flat & 15) * 4;                             \
        GLDS(kc + kqB + (size_t)((T0) + tt) * 512 + c4, &kL[BUF][j * 256]);   \
        GLDS(qc + kqB + (size_t)((T0) + tt) * 512 + c4, &qL[BUF][j * 256]);   \
    }                                                                         \
    _Pragma("unroll") for (int j = 0; j < 2; j++) {                           \
        int flat = j * 64 + lane;                                             \
        int tt = flat >> 2, c1 = flat & 3;                                    \
        GLDS4(vc + vaB + (size_t)((T0) + tt) * 1024 + c1, &vL[BUF][j * 64]);  \
        GLDS4(ab + vaB + (size_t)((T0) + tt) * 1024 + c1, &aL[BUF][j * 64]);  \
    }                                                                         \
    if (lane < CH)                                                            \
        GLDS4(betab + beB + (size_t)((T0) + lane) * 8, &bL[BUF][0]);          \
} while (0)

#define SCAN_LSTEP(BUF, TT) do {                                              \
    const float4 kk = *(const float4*)&kL[BUF][(TT) * 64 + ks * 4];           \
    const float4 qq = *(const float4*)&qL[BUF][(TT) * 64 + ks * 4];           \
    const float VV = vL[BUF][(TT) * 4 + vi];                                  \
    const float AA = aL[BUF][(TT) * 4 + vi];                                  \
    const float BB = bL[BUF][TT];                                             \
    float r0 = kk.x * S0, r1 = kk.y * S1;                                     \
    r0 = fmaf(kk.z, S2, r0); r1 = fmaf(kk.w, S3, r1);                         \
    float rr = reduce16(r0 + r1);                                             \
    float cc = BB * (rr - VV);                                                \
    float o0, o1;                                                             \
    S0 = fmaf(-cc, kk.x, AA * S0); o0 = qq.x * S0;                            \
    S1 = fmaf(-cc, kk.y, AA * S1); o1 = qq.y * S1;                            \
    S2 = fmaf(-cc, kk.z, AA * S2); o0 = fmaf(qq.z, S2, o0);                   \
    S3 = fmaf(-cc, kk.w, AA * S3); o1 = fmaf(qq.w, S3, o1);                   \
    float oo = reduce16(o0 + o1);                                             \
    if (ks == 0) oL[BUF][(TT) * 4 + vi] = oo;                                 \
} while (0)

__global__ __launch_bounds__(64) void scan_kernel(
    const float* __restrict__ qc, const float* __restrict__ kc,
    const float* __restrict__ vc, const float* __restrict__ ab,
    const float* __restrict__ betab, float* __restrict__ ob)
{
    __shared__ __attribute__((aligned(16))) float kL[2][CH * 64];
    __shared__ __attribute__((aligned(16))) float qL[2][CH * 64];
    __shared__ __attribute__((aligned(16))) float vL[2][CH * 4];
    __shared__ __attribute__((aligned(16))) float aL[2][CH * 4];
    __shared__ __attribute__((aligned(16))) float bL[2][CH];
    __shared__ __attribute__((aligned(16))) float oL[2][CH * 4];

    const int bid = blockIdx.x;
    const int bh = bid & 31, vg = bid >> 5;   // XCD-affinity: same bh -> same bid%8
    const int h = bh & 7, b = bh >> 3;
    const int lane = threadIdx.x;
    const int ks = lane & 15, vi = lane >> 4;

    const size_t kqB = (size_t)b * TDIM * 512 + (size_t)h * 64;
    const size_t vaB = (size_t)b * TDIM * 1024 + (size_t)h * 128 + (size_t)vg * 4;
    const size_t beB = (size_t)b * TDIM * 8 + h;

    float S0 = 0, S1 = 0, S2 = 0, S3 = 0;

    SCAN_STAGE(0, 0);
    __syncthreads();
    for (int chk = 0; chk < NCHUNK; chk++) {
        const int buf = chk & 1;
        const int nb = buf ^ 1;
        const int tn = (chk + 1 < NCHUNK) ? (chk + 1) * CH : 0;
        SCAN_STAGE(nb, tn);
#pragma unroll 8
        for (int t = 0; t < CH; t++) SCAN_LSTEP(buf, t);
        __syncthreads();  // drains next-chunk staging + oL visibility
        if (lane < CH)
            *(float4*)(ob + vaB + (size_t)(chk * CH + lane) * 1024) =
                *(const float4*)&oL[buf][lane * 4];
    }
}

// ---------------------------------------------------------------- LayerNorm(DV=128) + gate -> bf16
__global__ __launch_bounds__(256) void ln_gate_kernel(
    const float* __restrict__ ob, const float* __restrict__ g,
    const float* __restrict__ lnw, const float* __restrict__ lnb,
    __hip_bfloat16* __restrict__ opr)
{
    int row = blockIdx.x * 4 + (threadIdx.x >> 6);
    int lane = threadIdx.x & 63;
    size_t base = (size_t)row * 128 + lane * 2;
    float2 xv = *(const float2*)(ob + base);
    float s = xv.x + xv.y;
#pragma unroll
    for (int m = 1; m <= 32; m <<= 1) s += __shfl_xor(s, m);
    float mean = s * (1.0f / 128.0f);
    float d0 = xv.x - mean, d1 = xv.y - mean;
    float vs = d0 * d0 + d1 * d1;
#pragma unroll
    for (int m = 1; m <= 32; m <<= 1) vs += __shfl_xor(vs, m);
    float rstd = rsqrtf(vs * (1.0f / 128.0f) + 1e-5f);
    float2 gv = *(const float2*)(g + base);
    float w0 = lnw[lane * 2], w1 = lnw[lane * 2 + 1];
    float b0 = lnb[lane * 2], b1 = lnb[lane * 2 + 1];
    opr[base] = __float2bfloat16((d0 * rstd * w0 + b0) * gv.x);
    opr[base + 1] = __float2bfloat16((d1 * rstd * w1 + b1) * gv.y);
}

// ---------------------------------------------------------------- launch
extern "C" void kernel_launch(void* const* d_in, const int* in_sizes, int n_in,
                              void* d_out, int out_size, void* d_ws, size_t ws_size,
                              hipStream_t stream)
{
    const float* x    = (const float*)d_in[0];
    const float* Wq   = (const float*)d_in[1];
    const float* Wk   = (const float*)d_in[2];
    const float* Wv   = (const float*)d_in[3];
    const float* Wa   = (const float*)d_in[4];
    const float* ba   = (const float*)d_in[5];
    const float* Wb   = (const float*)d_in[6];
    const float* bb   = (const float*)d_in[7];
    const float* Wg   = (const float*)d_in[8];
    const float* Wo   = (const float*)d_in[9];
    const float* qc_w = (const float*)d_in[10];
    const float* qc_b = (const float*)d_in[11];
    const float* kc_w = (const float*)d_in[12];
    const float* kc_b = (const float*)d_in[13];
    const float* vc_w = (const float*)d_in[14];
    const float* vc_b = (const float*)d_in[15];
    const float* ln_w = (const float*)d_in[16];
    const float* ln_b = (const float*)d_in[17];
    float* out = (float*)d_out;

    char* W = (char*)d_ws;
    __hip_bfloat16* xbf  = (__hip_bfloat16*)(W + 0);            // 16777216
    __hip_bfloat16* wcat = (__hip_bfloat16*)(W + 16777216);     // 8650752
    __hip_bfloat16* wobf = (__hip_bfloat16*)(W + 25427968);     // 2097152
    float* qraw  = (float*)(W + 27525120);                      // 16777216
    float* kraw  = (float*)(W + 44302336);                      // 16777216
    float* vraw  = (float*)(W + 61079552);                      // 33554432
    float* abuf  = (float*)(W + 94633984);                      // 33554432
    float* betab = (float*)(W + 128188416);                     // 262144
    float* gbuf  = (float*)(W + 128450560);                     // 33554432
    float* kcb   = (float*)(W + 162004992);                     // 16777216
    float* vcb   = (float*)(W + 178782208);                     // 33554432
    float* qcb   = (float*)xbf;                 // reuse: xbf dead after gemm1
    float* obuf  = (float*)qraw;                // reuse: qraw+kraw dead after convs
    __hip_bfloat16* opr = (__hip_bfloat16*)vraw;// reuse: vraw dead after conv-v

    pack_f32_bf16_kernel<<<8192, 256, 0, stream>>>(x, xbf, 2097152);
    pack_w_kernel<<<16896, 256, 0, stream>>>(Wq, Wk, Wv, Wa, Wb, Wg, wcat);
    pack_f32_bf16_kernel<<<1024, 256, 0, stream>>>(Wo, wobf, 262144);
    gemm1_kernel<<<dim3(64, 33), 256, 0, stream>>>(xbf, wcat, qraw, kraw, vraw,
                                                   abuf, betab, gbuf, ba, bb);
    conv_silu_fused_kernel<<<65536, 256, 0, stream>>>(
        qraw, kraw, vraw, qc_w, qc_b, kc_w, kc_b, vc_w, vc_b, qcb, kcb, vcb);
    scan_kernel<<<1024, 64, 0, stream>>>(qcb, kcb, vcb, abuf, betab, obuf);
    ln_gate_kernel<<<16384, 256, 0, stream>>>(obuf, gbuf, ln_w, ln_b, opr);
    gemm2_kernel<<<dim3(64, 8), 256, 0, stream>>>(opr, wobf, out);
}